// Round 1
// baseline (595.747 us; speedup 1.0000x reference)
//
#include <hip/hip_runtime.h>

#define NB 16
#define NN 256
#define DD 128
#define NL 3
#define NE 32768
#define BN 4096   // NB*NN

// ---------------- helpers ----------------
__device__ __forceinline__ float siluf(float y) {
  return __fdividef(y, 1.0f + __expf(-y));
}

template<int CTRL>
__device__ __forceinline__ float dpp_add(float x) {
  int v = __builtin_amdgcn_update_dpp(0, __float_as_int(x), CTRL, 0xF, 0xF, true);
  return x + __int_as_float(v);
}

// sum across 32 lanes (halves independent): 4 DPP steps (16-group) + swizzle xor16
__device__ __forceinline__ float sum32(float x) {
  x = dpp_add<0xB1>(x);   // quad_perm [1,0,3,2]  (xor 1)
  x = dpp_add<0x4E>(x);   // quad_perm [2,3,0,1]  (xor 2)
  x = dpp_add<0x141>(x);  // row_half_mirror      (pairs across 4-groups in 8)
  x = dpp_add<0x140>(x);  // row_mirror           (pairs across 8-groups in 16)
  int v = __builtin_amdgcn_ds_swizzle(__float_as_int(x), 0x401F); // xor 16
  return x + __int_as_float(v);
}

__device__ __forceinline__ float sum64(float x) {
  x = sum32(x);
  return x + __shfl_xor(x, 32, 64);
}

// ---------------- kernels ----------------

// h[i][d] = x[i]*encW[d] + encb[d]
__global__ __launch_bounds__(256) void k_encode(
    const float* __restrict__ x, const float* __restrict__ W,
    const float* __restrict__ bb, float* __restrict__ h) {
  int t = blockIdx.x * 256 + threadIdx.x;   // 131072 threads, float4 each
  int i = t >> 5;
  int c = (t & 31) << 2;
  float xv = x[i];
  float4 w = *(const float4*)(W + c);
  float4 bv = *(const float4*)(bb + c);
  float4 o;
  o.x = fmaf(xv, w.x, bv.x); o.y = fmaf(xv, w.y, bv.y);
  o.z = fmaf(xv, w.z, bv.z); o.w = fmaf(xv, w.w, bv.w);
  *(float4*)(h + i * DD + c) = o;
}

// scatter-add adjacency (symmetrized)
__global__ __launch_bounds__(256) void k_scatter(
    const int* __restrict__ ei, const float* __restrict__ ea,
    float* __restrict__ adj) {
  int e = blockIdx.x * 256 + threadIdx.x;
  int g0 = ei[e];
  int g1 = ei[NE + e];
  float v = ea[e];
  int b = g0 >> 8;          // N = 256
  int s = g0 & 255;
  int d = g1 & 255;
  atomicAdd(adj + (b * NN + s) * NN + d, v);
  atomicAdd(adj + (b * NN + d) * NN + s, v);
}

// C1 = A@W1, C2 = A@W2   (A: BN x 128, W: 128 x 128)
__global__ __launch_bounds__(256) void k_gemm2(
    const float* __restrict__ A, const float* __restrict__ W1,
    const float* __restrict__ W2, float* __restrict__ C1, float* __restrict__ C2) {
  __shared__ float sa[8][128];
  int r = threadIdx.x >> 5;
  int c4 = (threadIdx.x & 31) << 2;
  int row0 = blockIdx.x << 3;
  ((float4*)&sa[0][0])[threadIdx.x] = ((const float4*)(A + row0 * DD))[threadIdx.x];
  __syncthreads();
  float4 a1 = {0.f, 0.f, 0.f, 0.f}, a2 = {0.f, 0.f, 0.f, 0.f};
  #pragma unroll 4
  for (int m = 0; m < DD; ++m) {
    float a = sa[r][m];
    float4 w1 = *(const float4*)(W1 + m * DD + c4);
    float4 w2 = *(const float4*)(W2 + m * DD + c4);
    a1.x = fmaf(a, w1.x, a1.x); a1.y = fmaf(a, w1.y, a1.y);
    a1.z = fmaf(a, w1.z, a1.z); a1.w = fmaf(a, w1.w, a1.w);
    a2.x = fmaf(a, w2.x, a2.x); a2.y = fmaf(a, w2.y, a2.y);
    a2.z = fmaf(a, w2.z, a2.z); a2.w = fmaf(a, w2.w, a2.w);
  }
  int rw = row0 + r;
  *(float4*)(C1 + rw * DD + c4) = a1;
  *(float4*)(C2 + rw * DD + c4) = a2;
}

// messages + aggregation: wave-per-i, lane owns d = {2l, 2l+1}
__global__ __launch_bounds__(1024) void k_messages(
    const float* __restrict__ hT, const float* __restrict__ hS,
    const float* __restrict__ adj, const float* __restrict__ wj,
    const float* __restrict__ mb, const float* __restrict__ mg,
    const float* __restrict__ mbe, float* __restrict__ agg) {
  __shared__ float sh[64 * 128];    // 32 KB: 64-row chunk of hS
  __shared__ float sadj[16 * 256];  // 16 KB: adj rows for this block's 16 i's
  int b = blockIdx.x >> 4;
  int i0 = (blockIdx.x & 15) << 4;
  {
    const float4* asrc = (const float4*)(adj + (b * NN + i0) * NN);
    ((float4*)sadj)[threadIdx.x] = asrc[threadIdx.x];   // 1024 float4 exactly
  }
  int w = threadIdx.x >> 6;
  int lane = threadIdx.x & 63;
  int i = i0 + w;
  int row = b * NN + i;
  int d0 = lane << 1;
  float2 ht  = *(const float2*)(hT + row * DD + d0);
  float2 wjv = *(const float2*)(wj + d0);
  float2 mbv = *(const float2*)(mb + d0);
  float2 gv  = *(const float2*)(mg + d0);
  float2 bev = *(const float2*)(mbe + d0);
  float htp0 = ht.x + mbv.x;
  float htp1 = ht.y + mbv.y;
  float acc0 = 0.f, acc1 = 0.f;
  const float* arow = sadj + w * NN;

  for (int c0 = 0; c0 < NN; c0 += 64) {
    __syncthreads();
    {
      const float4* hsrc = (const float4*)(hS + (b * NN + c0) * DD);
      float4* hdst = (float4*)sh;
      int t = threadIdx.x;
      hdst[t] = hsrc[t];
      hdst[t + 1024] = hsrc[t + 1024];
    }
    __syncthreads();
    #pragma unroll 2
    for (int jj = 0; jj < 64; ++jj) {
      float a = arow[c0 + jj];
      float2 hs = *(const float2*)(sh + jj * DD + d0);
      float pre0 = fmaf(a, wjv.x, htp0 + hs.x);
      float pre1 = fmaf(a, wjv.y, htp1 + hs.y);
      float s1 = sum64(pre0 + pre1);
      float s2 = sum64(fmaf(pre0, pre0, pre1 * pre1));
      float mean = s1 * 0.0078125f;
      float var = fmaf(-mean, mean, s2 * 0.0078125f);
      float rstd = rsqrtf(var + 1e-5f);
      float y0 = fmaf((pre0 - mean) * rstd, gv.x, bev.x);
      float y1 = fmaf((pre1 - mean) * rstd, gv.y, bev.y);
      acc0 += siluf(y0);
      acc1 += siluf(y1);
    }
    int li = i - c0;
    if (li >= 0 && li < 64) {   // subtract the j == i term (wave-uniform branch)
      float a = arow[i];
      float2 hs = *(const float2*)(sh + li * DD + d0);
      float pre0 = fmaf(a, wjv.x, htp0 + hs.x);
      float pre1 = fmaf(a, wjv.y, htp1 + hs.y);
      float s1 = sum64(pre0 + pre1);
      float s2 = sum64(fmaf(pre0, pre0, pre1 * pre1));
      float mean = s1 * 0.0078125f;
      float var = fmaf(-mean, mean, s2 * 0.0078125f);
      float rstd = rsqrtf(var + 1e-5f);
      float y0 = fmaf((pre0 - mean) * rstd, gv.x, bev.x);
      float y1 = fmaf((pre1 - mean) * rstd, gv.y, bev.y);
      acc0 -= siluf(y0);
      acc1 -= siluf(y1);
    }
  }
  *(float2*)(agg + row * DD + d0) = make_float2(acc0, acc1);
}

// u = [h|agg] @ W + ub;  h += silu(LN(u))
__global__ __launch_bounds__(256) void k_update(
    float* __restrict__ h, const float* __restrict__ agg,
    const float* __restrict__ W, const float* __restrict__ ub,
    const float* __restrict__ ug, const float* __restrict__ ube) {
  __shared__ float scat[8][256];
  int r = threadIdx.x >> 5;
  int c4 = (threadIdx.x & 31) << 2;
  int row0 = blockIdx.x << 3;
  {
    int t = threadIdx.x;                 // 256 float4 = 8 rows x 128
    float4 v = ((const float4*)(h + row0 * DD))[t];
    int f = t << 2; int rr = f >> 7; int mm = f & 127;
    *(float4*)&scat[rr][mm] = v;
    float4 va = ((const float4*)(agg + row0 * DD))[t];
    *(float4*)&scat[rr][DD + mm] = va;
  }
  __syncthreads();
  float4 acc = *(const float4*)(ub + c4);
  #pragma unroll 4
  for (int m = 0; m < 2 * DD; ++m) {
    float a = scat[r][m];
    float4 wv = *(const float4*)(W + m * DD + c4);
    acc.x = fmaf(a, wv.x, acc.x);
    acc.y = fmaf(a, wv.y, acc.y);
    acc.z = fmaf(a, wv.z, acc.z);
    acc.w = fmaf(a, wv.w, acc.w);
  }
  // LN over the 128 outputs of this row (32 lanes of a half-wave)
  float s1 = sum32((acc.x + acc.y) + (acc.z + acc.w));
  float s2 = sum32(fmaf(acc.x, acc.x, acc.y * acc.y) + fmaf(acc.z, acc.z, acc.w * acc.w));
  float mean = s1 * 0.0078125f;
  float var = fmaf(-mean, mean, s2 * 0.0078125f);
  float rstd = rsqrtf(var + 1e-5f);
  float4 g  = *(const float4*)(ug + c4);
  float4 be = *(const float4*)(ube + c4);
  float4 ho = *(const float4*)&scat[r][c4];
  float4 o;
  o.x = ho.x + siluf(fmaf((acc.x - mean) * rstd, g.x, be.x));
  o.y = ho.y + siluf(fmaf((acc.y - mean) * rstd, g.y, be.y));
  o.z = ho.z + siluf(fmaf((acc.z - mean) * rstd, g.z, be.z));
  o.w = ho.w + siluf(fmaf((acc.w - mean) * rstd, g.w, be.w));
  *(float4*)(h + (row0 + r) * DD + c4) = o;
}

// W2T[k][m] = W2[m][k]
__global__ __launch_bounds__(256) void k_w2t(
    const float* __restrict__ W2, float* __restrict__ W2T) {
  int t = blockIdx.x * 256 + threadIdx.x;  // 8192
  int m = t >> 6, k = t & 63;
  W2T[k * DD + m] = W2[m * 64 + k];
}

// decoder: thread-per-edge, s[] register-resident, W2T via uniform (scalar) loads
__global__ __launch_bounds__(256) void k_decoder(
    const int* __restrict__ ei, const float* __restrict__ ea,
    const float* __restrict__ P, const float* __restrict__ Q,
    const float* __restrict__ w1e, const float* __restrict__ b1,
    const float* __restrict__ W2T, const float* __restrict__ b2,
    const float* __restrict__ W3, const float* __restrict__ b3,
    float* __restrict__ out) {
  int e = blockIdx.x * 256 + threadIdx.x;
  int g0 = ei[e];
  int g1 = ei[NE + e];
  float av = ea[e];
  const float4* p4 = (const float4*)(P + g0 * DD);
  const float4* q4 = (const float4*)(Q + g1 * DD);
  float s[DD];
  #pragma unroll
  for (int m4 = 0; m4 < DD / 4; ++m4) {
    float4 p = p4[m4];
    float4 q = q4[m4];
    float4 wv = *(const float4*)(w1e + (m4 << 2));
    float4 bv = *(const float4*)(b1 + (m4 << 2));
    s[(m4 << 2) + 0] = siluf(fmaf(av, wv.x, (p.x + q.x) + bv.x));
    s[(m4 << 2) + 1] = siluf(fmaf(av, wv.y, (p.y + q.y) + bv.y));
    s[(m4 << 2) + 2] = siluf(fmaf(av, wv.z, (p.z + q.z) + bv.z));
    s[(m4 << 2) + 3] = siluf(fmaf(av, wv.w, (p.w + q.w) + bv.w));
  }
  float acc3 = 0.f;
  #pragma unroll 1
  for (int k2 = 0; k2 < 64; ++k2) {
    const float* wc = W2T + (k2 << 7);
    float t0 = b2[k2], t1 = 0.f, t2 = 0.f, t3 = 0.f;
    #pragma unroll
    for (int m = 0; m < DD; m += 4) {
      t0 = fmaf(s[m + 0], wc[m + 0], t0);
      t1 = fmaf(s[m + 1], wc[m + 1], t1);
      t2 = fmaf(s[m + 2], wc[m + 2], t2);
      t3 = fmaf(s[m + 3], wc[m + 3], t3);
    }
    acc3 = fmaf(siluf((t0 + t1) + (t2 + t3)), W3[k2], acc3);
  }
  out[e] = tanhf(acc3 + b3[0]);
}

// ---------------- launcher ----------------
extern "C" void kernel_launch(void* const* d_in, const int* in_sizes, int n_in,
                              void* d_out, int out_size, void* d_ws, size_t ws_size,
                              hipStream_t stream) {
  const float* x     = (const float*)d_in[0];
  const int*   ei    = (const int*)  d_in[1];
  const float* ea    = (const float*)d_in[2];
  // d_in[3] = batch (derivable: global_id >> 8)
  const float* encW  = (const float*)d_in[4];
  const float* encb  = (const float*)d_in[5];
  const float* msgW  = (const float*)d_in[6];
  const float* msgb  = (const float*)d_in[7];
  const float* msgg  = (const float*)d_in[8];
  const float* msgbe = (const float*)d_in[9];
  const float* updW  = (const float*)d_in[10];
  const float* updb  = (const float*)d_in[11];
  const float* updg  = (const float*)d_in[12];
  const float* updbe = (const float*)d_in[13];
  const float* dW1   = (const float*)d_in[14];
  const float* db1   = (const float*)d_in[15];
  const float* dW2   = (const float*)d_in[16];
  const float* db2   = (const float*)d_in[17];
  const float* dW3   = (const float*)d_in[18];
  const float* db3   = (const float*)d_in[19];
  float* out = (float*)d_out;

  float* h   = (float*)d_ws;             // BN*DD
  float* adj = h   + BN * DD;            // NB*NN*NN
  float* hT  = adj + NB * NN * NN;       // BN*DD  (also decoder P)
  float* hS  = hT  + BN * DD;            // BN*DD  (also decoder Q)
  float* agg = hS  + BN * DD;            // BN*DD
  float* W2T = agg + BN * DD;            // 64*128

  hipMemsetAsync(adj, 0, (size_t)NB * NN * NN * sizeof(float), stream);
  k_encode<<<512, 256, 0, stream>>>(x, encW, encb, h);
  k_scatter<<<NE / 256, 256, 0, stream>>>(ei, ea, adj);

  for (int l = 0; l < NL; ++l) {
    const float* Wl = msgW + (size_t)l * (2 * DD + 1) * DD;
    k_gemm2<<<BN / 8, 256, 0, stream>>>(h, Wl, Wl + DD * DD, hT, hS);
    k_messages<<<256, 1024, 0, stream>>>(hT, hS, adj,
        Wl + 2 * DD * DD, msgb + l * DD, msgg + l * DD, msgbe + l * DD, agg);
    k_update<<<BN / 8, 256, 0, stream>>>(h, agg, updW + (size_t)l * 2 * DD * DD,
        updb + l * DD, updg + l * DD, updbe + l * DD);
  }

  k_gemm2<<<BN / 8, 256, 0, stream>>>(h, dW1, dW1 + DD * DD, hT, hS); // P, Q
  k_w2t<<<32, 256, 0, stream>>>(dW2, W2T);
  k_decoder<<<NE / 256, 256, 0, stream>>>(ei, ea, hT, hS, dW1 + 2 * DD * DD, db1,
      W2T, db2, dW3, db3, out);
}

// Round 2
// 498.244 us; speedup vs baseline: 1.1957x; 1.1957x over previous
//
#include <hip/hip_runtime.h>

#define NB 16
#define NN 256
#define DD 128
#define NL 3
#define NE 32768
#define BN 4096   // NB*NN

// ---------------- helpers ----------------
__device__ __forceinline__ float siluf(float y) {
  return __fdividef(y, 1.0f + __expf(-y));
}

template<int CTRL>
__device__ __forceinline__ float dpp_add(float x) {
  int v = __builtin_amdgcn_update_dpp(0, __float_as_int(x), CTRL, 0xF, 0xF, true);
  return x + __int_as_float(v);
}

// sum across 32 lanes (the two 32-halves reduce independently)
__device__ __forceinline__ float sum32(float x) {
  x = dpp_add<0xB1>(x);   // quad_perm xor1
  x = dpp_add<0x4E>(x);   // quad_perm xor2
  x = dpp_add<0x141>(x);  // row_half_mirror
  x = dpp_add<0x140>(x);  // row_mirror
  int v = __builtin_amdgcn_ds_swizzle(__float_as_int(x), 0x401F); // xor 16
  return x + __int_as_float(v);
}

__device__ __forceinline__ float sum64(float x) {
  x = sum32(x);
  return x + __shfl_xor(x, 32, 64);
}

// ---------------- kernels ----------------

__global__ __launch_bounds__(256) void k_encode(
    const float* __restrict__ x, const float* __restrict__ W,
    const float* __restrict__ bb, float* __restrict__ h) {
  int t = blockIdx.x * 256 + threadIdx.x;
  int i = t >> 5;
  int c = (t & 31) << 2;
  float xv = x[i];
  float4 w = *(const float4*)(W + c);
  float4 bv = *(const float4*)(bb + c);
  float4 o;
  o.x = fmaf(xv, w.x, bv.x); o.y = fmaf(xv, w.y, bv.y);
  o.z = fmaf(xv, w.z, bv.z); o.w = fmaf(xv, w.w, bv.w);
  *(float4*)(h + i * DD + c) = o;
}

__global__ __launch_bounds__(256) void k_scatter(
    const int* __restrict__ ei, const float* __restrict__ ea,
    float* __restrict__ adj) {
  int e = blockIdx.x * 256 + threadIdx.x;
  int g0 = ei[e];
  int g1 = ei[NE + e];
  float v = ea[e];
  int b = g0 >> 8;
  int s = g0 & 255;
  int d = g1 & 255;
  atomicAdd(adj + (b * NN + s) * NN + d, v);
  atomicAdd(adj + (b * NN + d) * NN + s, v);
}

// wstat[l] = (E[w], E[w^2]) for wj of layer l
__global__ __launch_bounds__(64) void k_wprep(
    const float* __restrict__ msgW, float* __restrict__ wst) {
  int l = blockIdx.x;
  const float* wj = msgW + (size_t)l * (2 * DD + 1) * DD + 2 * DD * DD;
  int d0 = threadIdx.x << 1;
  float2 wv = *(const float2*)(wj + d0);
  float s1 = sum64(wv.x + wv.y);
  float s2 = sum64(fmaf(wv.x, wv.x, wv.y * wv.y));
  if (threadIdx.x == 0)
    *(float2*)(wst + 2 * l) = make_float2(s1 * 0.0078125f, s2 * 0.0078125f);
}

// C1 = A@W1 (+bias1), C2 = A@W2; optional per-row stats vs wj:
// statT[row] = (E[c1], E[c1^2], E[c1*w], 0), statS likewise for c2.
__global__ __launch_bounds__(256) void k_gemm2(
    const float* __restrict__ A, const float* __restrict__ W1,
    const float* __restrict__ W2, const float* __restrict__ bias1,
    const float* __restrict__ wj,
    float* __restrict__ C1, float* __restrict__ C2,
    float* __restrict__ statT, float* __restrict__ statS) {
  __shared__ float sa[8][128];
  int r = threadIdx.x >> 5;
  int c4 = (threadIdx.x & 31) << 2;
  int row0 = blockIdx.x << 3;
  ((float4*)&sa[0][0])[threadIdx.x] = ((const float4*)(A + row0 * DD))[threadIdx.x];
  __syncthreads();
  float4 a1 = {0.f, 0.f, 0.f, 0.f}, a2 = {0.f, 0.f, 0.f, 0.f};
  #pragma unroll 4
  for (int m = 0; m < DD; ++m) {
    float a = sa[r][m];
    float4 w1 = *(const float4*)(W1 + m * DD + c4);
    float4 w2 = *(const float4*)(W2 + m * DD + c4);
    a1.x = fmaf(a, w1.x, a1.x); a1.y = fmaf(a, w1.y, a1.y);
    a1.z = fmaf(a, w1.z, a1.z); a1.w = fmaf(a, w1.w, a1.w);
    a2.x = fmaf(a, w2.x, a2.x); a2.y = fmaf(a, w2.y, a2.y);
    a2.z = fmaf(a, w2.z, a2.z); a2.w = fmaf(a, w2.w, a2.w);
  }
  if (bias1) {
    float4 bv = *(const float4*)(bias1 + c4);
    a1.x += bv.x; a1.y += bv.y; a1.z += bv.z; a1.w += bv.w;
  }
  int rw = row0 + r;
  *(float4*)(C1 + rw * DD + c4) = a1;
  *(float4*)(C2 + rw * DD + c4) = a2;
  if (wj) {
    float4 wv = *(const float4*)(wj + c4);
    float s1t = sum32((a1.x + a1.y) + (a1.z + a1.w));
    float s2t = sum32(fmaf(a1.x, a1.x, a1.y * a1.y) + fmaf(a1.z, a1.z, a1.w * a1.w));
    float s3t = sum32(fmaf(a1.x, wv.x, a1.y * wv.y) + fmaf(a1.z, wv.z, a1.w * wv.w));
    float s1s = sum32((a2.x + a2.y) + (a2.z + a2.w));
    float s2s = sum32(fmaf(a2.x, a2.x, a2.y * a2.y) + fmaf(a2.z, a2.z, a2.w * a2.w));
    float s3s = sum32(fmaf(a2.x, wv.x, a2.y * wv.y) + fmaf(a2.z, wv.z, a2.w * wv.w));
    if ((threadIdx.x & 31) == 0) {
      const float inv = 0.0078125f;
      ((float4*)statT)[rw] = make_float4(s1t * inv, s2t * inv, s3t * inv, 0.f);
      ((float4*)statS)[rw] = make_float4(s1s * inv, s2s * inv, s3s * inv, 0.f);
    }
  }
}

// TS GEMM + closed-form LN moments: MR[b,i,j] = (rstd, -mean*rstd)
__global__ __launch_bounds__(256) void k_ts(
    const float* __restrict__ T, const float* __restrict__ S,
    const float* __restrict__ adj,
    const float* __restrict__ statT, const float* __restrict__ statS,
    const float* __restrict__ wst, float* __restrict__ MR) {
  __shared__ float sT[64][64];  // k-major: sT[k][i]
  __shared__ float sS[64][64];
  int b = blockIdx.x >> 4;
  int i0 = ((blockIdx.x >> 2) & 3) << 6;
  int j0 = (blockIdx.x & 3) << 6;
  int t = threadIdx.x;
  int ti = t >> 4, tj = t & 15;
  float acc[4][4] = {};
  int sr = t >> 2, scg = t & 3;
  const float* Trow = T + ((size_t)(b * NN + i0 + sr)) * DD + scg * 16;
  const float* Srow = S + ((size_t)(b * NN + j0 + sr)) * DD + scg * 16;
  for (int kc = 0; kc < 2; ++kc) {
    __syncthreads();
    #pragma unroll
    for (int m = 0; m < 4; ++m) {
      float4 v = *(const float4*)(Trow + kc * 64 + m * 4);
      int kk = scg * 16 + m * 4;
      sT[kk + 0][sr] = v.x; sT[kk + 1][sr] = v.y;
      sT[kk + 2][sr] = v.z; sT[kk + 3][sr] = v.w;
      float4 u = *(const float4*)(Srow + kc * 64 + m * 4);
      sS[kk + 0][sr] = u.x; sS[kk + 1][sr] = u.y;
      sS[kk + 2][sr] = u.z; sS[kk + 3][sr] = u.w;
    }
    __syncthreads();
    #pragma unroll 4
    for (int k = 0; k < 64; ++k) {
      float4 rt = *(const float4*)&sT[k][ti << 2];
      float4 rs = *(const float4*)&sS[k][tj << 2];
      acc[0][0] = fmaf(rt.x, rs.x, acc[0][0]);
      acc[0][1] = fmaf(rt.x, rs.y, acc[0][1]);
      acc[0][2] = fmaf(rt.x, rs.z, acc[0][2]);
      acc[0][3] = fmaf(rt.x, rs.w, acc[0][3]);
      acc[1][0] = fmaf(rt.y, rs.x, acc[1][0]);
      acc[1][1] = fmaf(rt.y, rs.y, acc[1][1]);
      acc[1][2] = fmaf(rt.y, rs.z, acc[1][2]);
      acc[1][3] = fmaf(rt.y, rs.w, acc[1][3]);
      acc[2][0] = fmaf(rt.z, rs.x, acc[2][0]);
      acc[2][1] = fmaf(rt.z, rs.y, acc[2][1]);
      acc[2][2] = fmaf(rt.z, rs.z, acc[2][2]);
      acc[2][3] = fmaf(rt.z, rs.w, acc[2][3]);
      acc[3][0] = fmaf(rt.w, rs.x, acc[3][0]);
      acc[3][1] = fmaf(rt.w, rs.y, acc[3][1]);
      acc[3][2] = fmaf(rt.w, rs.z, acc[3][2]);
      acc[3][3] = fmaf(rt.w, rs.w, acc[3][3]);
    }
  }
  float2 ws = *(const float2*)wst;
  float4 stT[4], stS[4];
  #pragma unroll
  for (int o = 0; o < 4; ++o) {
    stT[o] = ((const float4*)statT)[b * NN + i0 + (ti << 2) + o];
    stS[o] = ((const float4*)statS)[b * NN + j0 + (tj << 2) + o];
  }
  #pragma unroll
  for (int oi = 0; oi < 4; ++oi) {
    int row = b * NN + i0 + (ti << 2) + oi;
    float4 av = *(const float4*)(adj + (size_t)row * NN + j0 + (tj << 2));
    float R[4], NMR[4];
    #pragma unroll
    for (int oj = 0; oj < 4; ++oj) {
      float a = (oj == 0) ? av.x : (oj == 1) ? av.y : (oj == 2) ? av.z : av.w;
      float mean = stT[oi].x + stS[oj].x + a * ws.x;
      float e2 = stT[oi].y + stS[oj].y + a * a * ws.y
               + fmaf(acc[oi][oj], 0.015625f, 2.f * a * (stT[oi].z + stS[oj].z));
      float var = fmaf(-mean, mean, e2);
      float Rv = rsqrtf(var + 1e-5f);
      R[oj] = Rv;
      NMR[oj] = -mean * Rv;
    }
    float2* mrow = (float2*)MR + (size_t)row * NN + j0 + (tj << 2);
    *(float4*)(mrow)     = make_float4(R[0], NMR[0], R[1], NMR[1]);
    *(float4*)(mrow + 2) = make_float4(R[2], NMR[2], R[3], NMR[3]);
  }
}

// messages + aggregation, LN folded via precomputed (rstd, -mean*rstd)
__global__ __launch_bounds__(1024) void k_messages(
    const float* __restrict__ hT, const float* __restrict__ hS,
    const float* __restrict__ MR, const float* __restrict__ adj,
    const float* __restrict__ wj, const float* __restrict__ mg,
    const float* __restrict__ mbe, float* __restrict__ agg) {
  __shared__ float sh[64 * 128];    // 32 KB
  __shared__ float sadj[16 * 256];  // 16 KB
  __shared__ float2 smr[16 * 64];   // 8 KB
  int b = blockIdx.x >> 4;
  int i0 = (blockIdx.x & 15) << 4;
  {
    const float4* asrc = (const float4*)(adj + ((size_t)(b * NN + i0)) * NN);
    ((float4*)sadj)[threadIdx.x] = asrc[threadIdx.x];
  }
  int w = threadIdx.x >> 6;
  int lane = threadIdx.x & 63;
  int i = i0 + w;
  int row = b * NN + i;
  int d0 = lane << 1;
  float2 tv  = *(const float2*)(hT + (size_t)row * DD + d0);  // includes mb
  float2 wv  = *(const float2*)(wj + d0);
  float2 gv  = *(const float2*)(mg + d0);
  float2 bev = *(const float2*)(mbe + d0);
  float acc0 = 0.f, acc1 = 0.f;
  const float* arow = sadj + w * NN;
  int sj = threadIdx.x & 63;

  for (int c0 = 0; c0 < NN; c0 += 64) {
    __syncthreads();
    {
      const float4* hsrc = (const float4*)(hS + ((size_t)(b * NN + c0)) * DD);
      float4* hdst = (float4*)sh;
      hdst[threadIdx.x] = hsrc[threadIdx.x];
      hdst[threadIdx.x + 1024] = hsrc[threadIdx.x + 1024];
      smr[w * 64 + sj] = ((const float2*)MR)[((size_t)(b * NN + i0 + w)) * NN + c0 + sj];
    }
    __syncthreads();
    const float2* mrw = smr + w * 64;
    #pragma unroll 4
    for (int jj = 0; jj < 64; ++jj) {
      float2 mr = mrw[jj];
      float a = arow[c0 + jj];
      float2 hs = *(const float2*)(sh + jj * DD + d0);
      float aR = a * mr.x;
      float z0 = fmaf(mr.x, tv.x + hs.x, mr.y);
      z0 = fmaf(aR, wv.x, z0);
      float y0 = fmaf(gv.x, z0, bev.x);
      float z1 = fmaf(mr.x, tv.y + hs.y, mr.y);
      z1 = fmaf(aR, wv.y, z1);
      float y1 = fmaf(gv.y, z1, bev.y);
      acc0 += siluf(y0);
      acc1 += siluf(y1);
    }
    int li = i - c0;
    if (li >= 0 && li < 64) {   // subtract j == i term (wave-uniform)
      float2 mr = mrw[li];
      float a = arow[i];
      float2 hs = *(const float2*)(sh + li * DD + d0);
      float aR = a * mr.x;
      float z0 = fmaf(mr.x, tv.x + hs.x, mr.y);
      z0 = fmaf(aR, wv.x, z0);
      float y0 = fmaf(gv.x, z0, bev.x);
      float z1 = fmaf(mr.x, tv.y + hs.y, mr.y);
      z1 = fmaf(aR, wv.y, z1);
      float y1 = fmaf(gv.y, z1, bev.y);
      acc0 -= siluf(y0);
      acc1 -= siluf(y1);
    }
  }
  *(float2*)(agg + (size_t)row * DD + d0) = make_float2(acc0, acc1);
}

// u = [h|agg] @ W + ub;  h += silu(LN(u))
__global__ __launch_bounds__(256) void k_update(
    float* __restrict__ h, const float* __restrict__ agg,
    const float* __restrict__ W, const float* __restrict__ ub,
    const float* __restrict__ ug, const float* __restrict__ ube) {
  __shared__ float scat[8][256];
  int r = threadIdx.x >> 5;
  int c4 = (threadIdx.x & 31) << 2;
  int row0 = blockIdx.x << 3;
  {
    int t = threadIdx.x;
    float4 v = ((const float4*)(h + row0 * DD))[t];
    int f = t << 2; int rr = f >> 7; int mm = f & 127;
    *(float4*)&scat[rr][mm] = v;
    float4 va = ((const float4*)(agg + row0 * DD))[t];
    *(float4*)&scat[rr][DD + mm] = va;
  }
  __syncthreads();
  float4 acc = *(const float4*)(ub + c4);
  #pragma unroll 4
  for (int m = 0; m < 2 * DD; ++m) {
    float a = scat[r][m];
    float4 wv = *(const float4*)(W + m * DD + c4);
    acc.x = fmaf(a, wv.x, acc.x);
    acc.y = fmaf(a, wv.y, acc.y);
    acc.z = fmaf(a, wv.z, acc.z);
    acc.w = fmaf(a, wv.w, acc.w);
  }
  float s1 = sum32((acc.x + acc.y) + (acc.z + acc.w));
  float s2 = sum32(fmaf(acc.x, acc.x, acc.y * acc.y) + fmaf(acc.z, acc.z, acc.w * acc.w));
  float mean = s1 * 0.0078125f;
  float var = fmaf(-mean, mean, s2 * 0.0078125f);
  float rstd = rsqrtf(var + 1e-5f);
  float4 g  = *(const float4*)(ug + c4);
  float4 be = *(const float4*)(ube + c4);
  float4 ho = *(const float4*)&scat[r][c4];
  float4 o;
  o.x = ho.x + siluf(fmaf((acc.x - mean) * rstd, g.x, be.x));
  o.y = ho.y + siluf(fmaf((acc.y - mean) * rstd, g.y, be.y));
  o.z = ho.z + siluf(fmaf((acc.z - mean) * rstd, g.z, be.z));
  o.w = ho.w + siluf(fmaf((acc.w - mean) * rstd, g.w, be.w));
  *(float4*)(h + (row0 + r) * DD + c4) = o;
}

__global__ __launch_bounds__(256) void k_w2t(
    const float* __restrict__ W2, float* __restrict__ W2T) {
  int t = blockIdx.x * 256 + threadIdx.x;
  int m = t >> 6, k = t & 63;
  W2T[k * DD + m] = W2[m * 64 + k];
}

__global__ __launch_bounds__(256) void k_decoder(
    const int* __restrict__ ei, const float* __restrict__ ea,
    const float* __restrict__ P, const float* __restrict__ Q,
    const float* __restrict__ w1e, const float* __restrict__ b1,
    const float* __restrict__ W2T, const float* __restrict__ b2,
    const float* __restrict__ W3, const float* __restrict__ b3,
    float* __restrict__ out) {
  int e = blockIdx.x * 256 + threadIdx.x;
  int g0 = ei[e];
  int g1 = ei[NE + e];
  float av = ea[e];
  const float4* p4 = (const float4*)(P + (size_t)g0 * DD);
  const float4* q4 = (const float4*)(Q + (size_t)g1 * DD);
  float s[DD];
  #pragma unroll
  for (int m4 = 0; m4 < DD / 4; ++m4) {
    float4 p = p4[m4];
    float4 q = q4[m4];
    float4 wv = *(const float4*)(w1e + (m4 << 2));
    float4 bv = *(const float4*)(b1 + (m4 << 2));
    s[(m4 << 2) + 0] = siluf(fmaf(av, wv.x, (p.x + q.x) + bv.x));
    s[(m4 << 2) + 1] = siluf(fmaf(av, wv.y, (p.y + q.y) + bv.y));
    s[(m4 << 2) + 2] = siluf(fmaf(av, wv.z, (p.z + q.z) + bv.z));
    s[(m4 << 2) + 3] = siluf(fmaf(av, wv.w, (p.w + q.w) + bv.w));
  }
  float acc3 = 0.f;
  #pragma unroll 1
  for (int k2 = 0; k2 < 64; ++k2) {
    const float* wc = W2T + (k2 << 7);
    float t0 = b2[k2], t1 = 0.f, t2 = 0.f, t3 = 0.f;
    #pragma unroll
    for (int m = 0; m < DD; m += 4) {
      t0 = fmaf(s[m + 0], wc[m + 0], t0);
      t1 = fmaf(s[m + 1], wc[m + 1], t1);
      t2 = fmaf(s[m + 2], wc[m + 2], t2);
      t3 = fmaf(s[m + 3], wc[m + 3], t3);
    }
    acc3 = fmaf(siluf((t0 + t1) + (t2 + t3)), W3[k2], acc3);
  }
  out[e] = tanhf(acc3 + b3[0]);
}

// ---------------- launcher ----------------
extern "C" void kernel_launch(void* const* d_in, const int* in_sizes, int n_in,
                              void* d_out, int out_size, void* d_ws, size_t ws_size,
                              hipStream_t stream) {
  const float* x     = (const float*)d_in[0];
  const int*   ei    = (const int*)  d_in[1];
  const float* ea    = (const float*)d_in[2];
  const float* encW  = (const float*)d_in[4];
  const float* encb  = (const float*)d_in[5];
  const float* msgW  = (const float*)d_in[6];
  const float* msgb  = (const float*)d_in[7];
  const float* msgg  = (const float*)d_in[8];
  const float* msgbe = (const float*)d_in[9];
  const float* updW  = (const float*)d_in[10];
  const float* updb  = (const float*)d_in[11];
  const float* updg  = (const float*)d_in[12];
  const float* updbe = (const float*)d_in[13];
  const float* dW1   = (const float*)d_in[14];
  const float* db1   = (const float*)d_in[15];
  const float* dW2   = (const float*)d_in[16];
  const float* db2   = (const float*)d_in[17];
  const float* dW3   = (const float*)d_in[18];
  const float* db3   = (const float*)d_in[19];
  float* out = (float*)d_out;

  float* h     = (float*)d_ws;              // BN*DD
  float* adj   = h     + BN * DD;           // NB*NN*NN
  float* hT    = adj   + NB * NN * NN;      // BN*DD (t = h@Wt + mb; decoder P)
  float* hS    = hT    + BN * DD;           // BN*DD (s = h@Ws; decoder Q)
  float* agg   = hS    + BN * DD;           // BN*DD
  float* W2T   = agg   + BN * DD;           // 64*128
  float* statT = W2T   + 64 * DD;           // BN*4
  float* statS = statT + BN * 4;            // BN*4
  float* wst   = statS + BN * 4;            // 8
  float* MR    = wst   + 8;                 // NB*NN*NN*2 (rstd, -mean*rstd)

  hipMemsetAsync(adj, 0, (size_t)NB * NN * NN * sizeof(float), stream);
  k_encode<<<512, 256, 0, stream>>>(x, encW, encb, h);
  k_scatter<<<NE / 256, 256, 0, stream>>>(ei, ea, adj);
  k_wprep<<<NL, 64, 0, stream>>>(msgW, wst);

  for (int l = 0; l < NL; ++l) {
    const float* Wl = msgW + (size_t)l * (2 * DD + 1) * DD;
    const float* wjl = Wl + 2 * DD * DD;
    k_gemm2<<<BN / 8, 256, 0, stream>>>(h, Wl, Wl + DD * DD, msgb + l * DD, wjl,
                                        hT, hS, statT, statS);
    k_ts<<<256, 256, 0, stream>>>(hT, hS, adj, statT, statS, wst + 2 * l, MR);
    k_messages<<<256, 1024, 0, stream>>>(hT, hS, MR, adj, wjl,
        msgg + l * DD, msgbe + l * DD, agg);
    k_update<<<BN / 8, 256, 0, stream>>>(h, agg, updW + (size_t)l * 2 * DD * DD,
        updb + l * DD, updg + l * DD, updbe + l * DD);
  }

  k_gemm2<<<BN / 8, 256, 0, stream>>>(h, dW1, dW1 + DD * DD, nullptr, nullptr,
                                      hT, hS, statT, statS);
  k_w2t<<<32, 256, 0, stream>>>(dW2, W2T);
  k_decoder<<<NE / 256, 256, 0, stream>>>(ei, ea, hT, hS, dW1 + 2 * DD * DD, db1,
      W2T, db2, dW3, db3, out);
}

// Round 3
// 387.192 us; speedup vs baseline: 1.5386x; 1.2868x over previous
//
#include <hip/hip_runtime.h>

#define NB 16
#define NN 256
#define DD 128
#define NL 3
#define NE 32768
#define BN 4096   // NB*NN

// ---------------- helpers ----------------
__device__ __forceinline__ float siluf(float y) {
  return __fdividef(y, 1.0f + __expf(-y));
}

template<int CTRL>
__device__ __forceinline__ float dpp_add(float x) {
  int v = __builtin_amdgcn_update_dpp(0, __float_as_int(x), CTRL, 0xF, 0xF, true);
  return x + __int_as_float(v);
}

// sum across 32 lanes (the two 32-halves reduce independently)
__device__ __forceinline__ float sum32(float x) {
  x = dpp_add<0xB1>(x);   // quad_perm xor1
  x = dpp_add<0x4E>(x);   // quad_perm xor2
  x = dpp_add<0x141>(x);  // row_half_mirror
  x = dpp_add<0x140>(x);  // row_mirror
  int v = __builtin_amdgcn_ds_swizzle(__float_as_int(x), 0x401F); // xor 16
  return x + __int_as_float(v);
}

__device__ __forceinline__ float sum64(float x) {
  x = sum32(x);
  return x + __shfl_xor(x, 32, 64);
}

// ---------------- kernels ----------------

__global__ __launch_bounds__(256) void k_encode(
    const float* __restrict__ x, const float* __restrict__ W,
    const float* __restrict__ bb, float* __restrict__ h) {
  int t = blockIdx.x * 256 + threadIdx.x;
  int i = t >> 5;
  int c = (t & 31) << 2;
  float xv = x[i];
  float4 w = *(const float4*)(W + c);
  float4 bv = *(const float4*)(bb + c);
  float4 o;
  o.x = fmaf(xv, w.x, bv.x); o.y = fmaf(xv, w.y, bv.y);
  o.z = fmaf(xv, w.z, bv.z); o.w = fmaf(xv, w.w, bv.w);
  *(float4*)(h + i * DD + c) = o;
}

__global__ __launch_bounds__(256) void k_scatter(
    const int* __restrict__ ei, const float* __restrict__ ea,
    float* __restrict__ adj) {
  int e = blockIdx.x * 256 + threadIdx.x;
  int g0 = ei[e];
  int g1 = ei[NE + e];
  float v = ea[e];
  int b = g0 >> 8;
  int s = g0 & 255;
  int d = g1 & 255;
  atomicAdd(adj + (b * NN + s) * NN + d, v);
  atomicAdd(adj + (b * NN + d) * NN + s, v);
}

// wstat[l] = (E[w], E[w^2]) for wj of layer l
__global__ __launch_bounds__(64) void k_wprep(
    const float* __restrict__ msgW, float* __restrict__ wst) {
  int l = blockIdx.x;
  const float* wj = msgW + (size_t)l * (2 * DD + 1) * DD + 2 * DD * DD;
  int d0 = threadIdx.x << 1;
  float2 wv = *(const float2*)(wj + d0);
  float s1 = sum64(wv.x + wv.y);
  float s2 = sum64(fmaf(wv.x, wv.x, wv.y * wv.y));
  if (threadIdx.x == 0)
    *(float2*)(wst + 2 * l) = make_float2(s1 * 0.0078125f, s2 * 0.0078125f);
}

// C1 = A@W1 (+bias1), C2 = A@W2; optional per-row stats vs wj.
__global__ __launch_bounds__(256) void k_gemm2(
    const float* __restrict__ A, const float* __restrict__ W1,
    const float* __restrict__ W2, const float* __restrict__ bias1,
    const float* __restrict__ wj,
    float* __restrict__ C1, float* __restrict__ C2,
    float* __restrict__ statT, float* __restrict__ statS) {
  __shared__ float sa[8][128];
  int r = threadIdx.x >> 5;
  int c4 = (threadIdx.x & 31) << 2;
  int row0 = blockIdx.x << 3;
  ((float4*)&sa[0][0])[threadIdx.x] = ((const float4*)(A + row0 * DD))[threadIdx.x];
  __syncthreads();
  float4 a1 = {0.f, 0.f, 0.f, 0.f}, a2 = {0.f, 0.f, 0.f, 0.f};
  #pragma unroll 4
  for (int m = 0; m < DD; ++m) {
    float a = sa[r][m];
    float4 w1 = *(const float4*)(W1 + m * DD + c4);
    float4 w2 = *(const float4*)(W2 + m * DD + c4);
    a1.x = fmaf(a, w1.x, a1.x); a1.y = fmaf(a, w1.y, a1.y);
    a1.z = fmaf(a, w1.z, a1.z); a1.w = fmaf(a, w1.w, a1.w);
    a2.x = fmaf(a, w2.x, a2.x); a2.y = fmaf(a, w2.y, a2.y);
    a2.z = fmaf(a, w2.z, a2.z); a2.w = fmaf(a, w2.w, a2.w);
  }
  if (bias1) {
    float4 bv = *(const float4*)(bias1 + c4);
    a1.x += bv.x; a1.y += bv.y; a1.z += bv.z; a1.w += bv.w;
  }
  int rw = row0 + r;
  *(float4*)(C1 + rw * DD + c4) = a1;
  *(float4*)(C2 + rw * DD + c4) = a2;
  if (wj) {
    float4 wv = *(const float4*)(wj + c4);
    float s1t = sum32((a1.x + a1.y) + (a1.z + a1.w));
    float s2t = sum32(fmaf(a1.x, a1.x, a1.y * a1.y) + fmaf(a1.z, a1.z, a1.w * a1.w));
    float s3t = sum32(fmaf(a1.x, wv.x, a1.y * wv.y) + fmaf(a1.z, wv.z, a1.w * wv.w));
    float s1s = sum32((a2.x + a2.y) + (a2.z + a2.w));
    float s2s = sum32(fmaf(a2.x, a2.x, a2.y * a2.y) + fmaf(a2.z, a2.z, a2.w * a2.w));
    float s3s = sum32(fmaf(a2.x, wv.x, a2.y * wv.y) + fmaf(a2.z, wv.z, a2.w * wv.w));
    if ((threadIdx.x & 31) == 0) {
      const float inv = 0.0078125f;
      ((float4*)statT)[rw] = make_float4(s1t * inv, s2t * inv, s3t * inv, 0.f);
      ((float4*)statS)[rw] = make_float4(s1s * inv, s2s * inv, s3s * inv, 0.f);
    }
  }
}

// TS GEMM + closed-form LN moments: MR[b,i,j] = (rstd, -mean*rstd)
__global__ __launch_bounds__(256) void k_ts(
    const float* __restrict__ T, const float* __restrict__ S,
    const float* __restrict__ adj,
    const float* __restrict__ statT, const float* __restrict__ statS,
    const float* __restrict__ wst, float* __restrict__ MR) {
  __shared__ float sT[64][64];  // k-major: sT[k][i]
  __shared__ float sS[64][64];
  int b = blockIdx.x >> 4;
  int i0 = ((blockIdx.x >> 2) & 3) << 6;
  int j0 = (blockIdx.x & 3) << 6;
  int t = threadIdx.x;
  int ti = t >> 4, tj = t & 15;
  float acc[4][4] = {};
  int sr = t >> 2, scg = t & 3;
  const float* Trow = T + ((size_t)(b * NN + i0 + sr)) * DD + scg * 16;
  const float* Srow = S + ((size_t)(b * NN + j0 + sr)) * DD + scg * 16;
  for (int kc = 0; kc < 2; ++kc) {
    __syncthreads();
    #pragma unroll
    for (int m = 0; m < 4; ++m) {
      float4 v = *(const float4*)(Trow + kc * 64 + m * 4);
      int kk = scg * 16 + m * 4;
      sT[kk + 0][sr] = v.x; sT[kk + 1][sr] = v.y;
      sT[kk + 2][sr] = v.z; sT[kk + 3][sr] = v.w;
      float4 u = *(const float4*)(Srow + kc * 64 + m * 4);
      sS[kk + 0][sr] = u.x; sS[kk + 1][sr] = u.y;
      sS[kk + 2][sr] = u.z; sS[kk + 3][sr] = u.w;
    }
    __syncthreads();
    #pragma unroll 4
    for (int k = 0; k < 64; ++k) {
      float4 rt = *(const float4*)&sT[k][ti << 2];
      float4 rs = *(const float4*)&sS[k][tj << 2];
      acc[0][0] = fmaf(rt.x, rs.x, acc[0][0]);
      acc[0][1] = fmaf(rt.x, rs.y, acc[0][1]);
      acc[0][2] = fmaf(rt.x, rs.z, acc[0][2]);
      acc[0][3] = fmaf(rt.x, rs.w, acc[0][3]);
      acc[1][0] = fmaf(rt.y, rs.x, acc[1][0]);
      acc[1][1] = fmaf(rt.y, rs.y, acc[1][1]);
      acc[1][2] = fmaf(rt.y, rs.z, acc[1][2]);
      acc[1][3] = fmaf(rt.y, rs.w, acc[1][3]);
      acc[2][0] = fmaf(rt.z, rs.x, acc[2][0]);
      acc[2][1] = fmaf(rt.z, rs.y, acc[2][1]);
      acc[2][2] = fmaf(rt.z, rs.z, acc[2][2]);
      acc[2][3] = fmaf(rt.z, rs.w, acc[2][3]);
      acc[3][0] = fmaf(rt.w, rs.x, acc[3][0]);
      acc[3][1] = fmaf(rt.w, rs.y, acc[3][1]);
      acc[3][2] = fmaf(rt.w, rs.z, acc[3][2]);
      acc[3][3] = fmaf(rt.w, rs.w, acc[3][3]);
    }
  }
  float2 ws = *(const float2*)wst;
  float4 stT[4], stS[4];
  #pragma unroll
  for (int o = 0; o < 4; ++o) {
    stT[o] = ((const float4*)statT)[b * NN + i0 + (ti << 2) + o];
    stS[o] = ((const float4*)statS)[b * NN + j0 + (tj << 2) + o];
  }
  #pragma unroll
  for (int oi = 0; oi < 4; ++oi) {
    int row = b * NN + i0 + (ti << 2) + oi;
    float4 av = *(const float4*)(adj + (size_t)row * NN + j0 + (tj << 2));
    float R[4], NMR[4];
    #pragma unroll
    for (int oj = 0; oj < 4; ++oj) {
      float a = (oj == 0) ? av.x : (oj == 1) ? av.y : (oj == 2) ? av.z : av.w;
      float mean = stT[oi].x + stS[oj].x + a * ws.x;
      float e2 = stT[oi].y + stS[oj].y + a * a * ws.y
               + fmaf(acc[oi][oj], 0.015625f, 2.f * a * (stT[oi].z + stS[oj].z));
      float var = fmaf(-mean, mean, e2);
      float Rv = rsqrtf(var + 1e-5f);
      R[oj] = Rv;
      NMR[oj] = -mean * Rv;
    }
    float2* mrow = (float2*)MR + (size_t)row * NN + j0 + (tj << 2);
    *(float4*)(mrow)     = make_float4(R[0], NMR[0], R[1], NMR[1]);
    *(float4*)(mrow + 2) = make_float4(R[2], NMR[2], R[3], NMR[3]);
  }
}

// messages + aggregation: 8 waves/block, wave-per-i, register-prefetch dbuf
__global__ __launch_bounds__(512, 4) void k_messages(
    const float* __restrict__ hT, const float* __restrict__ hS,
    const float* __restrict__ MR, const float* __restrict__ adj,
    const float* __restrict__ wj, const float* __restrict__ mg,
    const float* __restrict__ mbe, float* __restrict__ agg) {
  __shared__ float sh[64 * 128];     // 32 KB: current 64-row chunk of hS
  __shared__ float sadj[8 * 256];    // 8 KB: adj rows for this block's 8 i's
  __shared__ float smr[8 * 64 * 2];  // 4 KB: (rstd, nmr) for current chunk
  const float LN2 = 0.6931471805599453f;
  const float L2E = 1.4426950408889634f;
  int b = blockIdx.x >> 5;
  int i0 = (blockIdx.x & 31) << 3;
  int t = threadIdx.x;
  // adj rows: 8*256 floats = 512 float4, one per thread
  ((float4*)sadj)[t] = ((const float4*)(adj + (size_t)(b * NN + i0) * NN))[t];

  int w = t >> 6, lane = t & 63;
  int i = i0 + w, row = b * NN + i;
  int d0 = lane << 1;
  float2 tv = *(const float2*)(hT + (size_t)row * DD + d0);  // includes mb
  float2 wv = *(const float2*)(wj + d0);
  float2 gv = *(const float2*)(mg + d0);
  float2 bev = *(const float2*)(mbe + d0);
  float G0 = gv.x * L2E, G1 = gv.y * L2E;
  float BE0 = bev.x * L2E, BE1 = bev.y * L2E;
  float acc0 = 0.f, acc1 = 0.f;

  const float4* hsrc = (const float4*)(hS + (size_t)(b * NN) * DD);
  const float2* mrsrc = (const float2*)MR + (size_t)(b * NN + i0 + (t >> 6)) * NN + (t & 63);

  // prefetch chunk 0
  float4 p0 = hsrc[t], p1 = hsrc[t + 512], p2 = hsrc[t + 1024], p3 = hsrc[t + 1536];
  float2 pm = mrsrc[0];
  ((float4*)sh)[t] = p0; ((float4*)sh)[t + 512] = p1;
  ((float4*)sh)[t + 1024] = p2; ((float4*)sh)[t + 1536] = p3;
  ((float2*)smr)[t] = pm;
  __syncthreads();

  const float* arowb = sadj + w * NN;
  const float2* mrw = (const float2*)smr + w * 64;

  for (int c = 0; c < 4; ++c) {
    if (c < 3) {  // issue next-chunk loads; they stay in flight across compute
      const float4* hn = hsrc + (c + 1) * 2048;
      p0 = hn[t]; p1 = hn[t + 512]; p2 = hn[t + 1024]; p3 = hn[t + 1536];
      pm = mrsrc[(c + 1) * 64];
    }
    const float* arow = arowb + c * 64;
    #pragma unroll 4
    for (int jj = 0; jj < 64; ++jj) {
      float2 mr = mrw[jj];
      float a = arow[jj];
      float2 hs = *(const float2*)(sh + jj * DD + d0);
      float v0 = tv.x + hs.x; v0 = fmaf(a, wv.x, v0);
      float v1 = tv.y + hs.y; v1 = fmaf(a, wv.y, v1);
      float z0 = fmaf(mr.x, v0, mr.y);
      float z1 = fmaf(mr.x, v1, mr.y);
      float yl0 = fmaf(G0, z0, BE0);
      float yl1 = fmaf(G1, z1, BE1);
      float e0 = __builtin_amdgcn_exp2f(-yl0);
      float e1 = __builtin_amdgcn_exp2f(-yl1);
      float den0 = 1.0f + e0, den1 = 1.0f + e1;
      float r = __builtin_amdgcn_rcpf(den0 * den1);
      acc0 = fmaf((yl0 * den1) * r, LN2, acc0);
      acc1 = fmaf((yl1 * den0) * r, LN2, acc1);
    }
    if ((i >> 6) == c) {  // subtract j == i term (wave-uniform)
      int li = i & 63;
      float2 mr = mrw[li];
      float a = arow[li];
      float2 hs = *(const float2*)(sh + li * DD + d0);
      float v0 = tv.x + hs.x; v0 = fmaf(a, wv.x, v0);
      float v1 = tv.y + hs.y; v1 = fmaf(a, wv.y, v1);
      float z0 = fmaf(mr.x, v0, mr.y);
      float z1 = fmaf(mr.x, v1, mr.y);
      float yl0 = fmaf(G0, z0, BE0);
      float yl1 = fmaf(G1, z1, BE1);
      float e0 = __builtin_amdgcn_exp2f(-yl0);
      float e1 = __builtin_amdgcn_exp2f(-yl1);
      float den0 = 1.0f + e0, den1 = 1.0f + e1;
      float r = __builtin_amdgcn_rcpf(den0 * den1);
      acc0 = fmaf((yl0 * den1) * r, -LN2, acc0);
      acc1 = fmaf((yl1 * den0) * r, -LN2, acc1);
    }
    __syncthreads();
    if (c < 3) {
      ((float4*)sh)[t] = p0; ((float4*)sh)[t + 512] = p1;
      ((float4*)sh)[t + 1024] = p2; ((float4*)sh)[t + 1536] = p3;
      ((float2*)smr)[t] = pm;
      __syncthreads();
    }
  }
  *(float2*)(agg + (size_t)row * DD + d0) = make_float2(acc0, acc1);
}

// u = [h|agg] @ W + ub;  h += silu(LN(u))
__global__ __launch_bounds__(256) void k_update(
    float* __restrict__ h, const float* __restrict__ agg,
    const float* __restrict__ W, const float* __restrict__ ub,
    const float* __restrict__ ug, const float* __restrict__ ube) {
  __shared__ float scat[8][256];
  int r = threadIdx.x >> 5;
  int c4 = (threadIdx.x & 31) << 2;
  int row0 = blockIdx.x << 3;
  {
    int t = threadIdx.x;
    float4 v = ((const float4*)(h + row0 * DD))[t];
    int f = t << 2; int rr = f >> 7; int mm = f & 127;
    *(float4*)&scat[rr][mm] = v;
    float4 va = ((const float4*)(agg + row0 * DD))[t];
    *(float4*)&scat[rr][DD + mm] = va;
  }
  __syncthreads();
  float4 acc = *(const float4*)(ub + c4);
  #pragma unroll 4
  for (int m = 0; m < 2 * DD; ++m) {
    float a = scat[r][m];
    float4 wv = *(const float4*)(W + m * DD + c4);
    acc.x = fmaf(a, wv.x, acc.x);
    acc.y = fmaf(a, wv.y, acc.y);
    acc.z = fmaf(a, wv.z, acc.z);
    acc.w = fmaf(a, wv.w, acc.w);
  }
  float s1 = sum32((acc.x + acc.y) + (acc.z + acc.w));
  float s2 = sum32(fmaf(acc.x, acc.x, acc.y * acc.y) + fmaf(acc.z, acc.z, acc.w * acc.w));
  float mean = s1 * 0.0078125f;
  float var = fmaf(-mean, mean, s2 * 0.0078125f);
  float rstd = rsqrtf(var + 1e-5f);
  float4 g  = *(const float4*)(ug + c4);
  float4 be = *(const float4*)(ube + c4);
  float4 ho = *(const float4*)&scat[r][c4];
  float4 o;
  o.x = ho.x + siluf(fmaf((acc.x - mean) * rstd, g.x, be.x));
  o.y = ho.y + siluf(fmaf((acc.y - mean) * rstd, g.y, be.y));
  o.z = ho.z + siluf(fmaf((acc.z - mean) * rstd, g.z, be.z));
  o.w = ho.w + siluf(fmaf((acc.w - mean) * rstd, g.w, be.w));
  *(float4*)(h + (row0 + r) * DD + c4) = o;
}

__global__ __launch_bounds__(256) void k_w2t(
    const float* __restrict__ W2, float* __restrict__ W2T) {
  int t = blockIdx.x * 256 + threadIdx.x;
  int m = t >> 6, k = t & 63;
  W2T[k * DD + m] = W2[m * 64 + k];
}

__global__ __launch_bounds__(256) void k_decoder(
    const int* __restrict__ ei, const float* __restrict__ ea,
    const float* __restrict__ P, const float* __restrict__ Q,
    const float* __restrict__ w1e, const float* __restrict__ b1,
    const float* __restrict__ W2T, const float* __restrict__ b2,
    const float* __restrict__ W3, const float* __restrict__ b3,
    float* __restrict__ out) {
  int e = blockIdx.x * 256 + threadIdx.x;
  int g0 = ei[e];
  int g1 = ei[NE + e];
  float av = ea[e];
  const float4* p4 = (const float4*)(P + (size_t)g0 * DD);
  const float4* q4 = (const float4*)(Q + (size_t)g1 * DD);
  float s[DD];
  #pragma unroll
  for (int m4 = 0; m4 < DD / 4; ++m4) {
    float4 p = p4[m4];
    float4 q = q4[m4];
    float4 wv = *(const float4*)(w1e + (m4 << 2));
    float4 bv = *(const float4*)(b1 + (m4 << 2));
    s[(m4 << 2) + 0] = siluf(fmaf(av, wv.x, (p.x + q.x) + bv.x));
    s[(m4 << 2) + 1] = siluf(fmaf(av, wv.y, (p.y + q.y) + bv.y));
    s[(m4 << 2) + 2] = siluf(fmaf(av, wv.z, (p.z + q.z) + bv.z));
    s[(m4 << 2) + 3] = siluf(fmaf(av, wv.w, (p.w + q.w) + bv.w));
  }
  float acc3 = 0.f;
  #pragma unroll 1
  for (int k2 = 0; k2 < 64; ++k2) {
    const float* wc = W2T + (k2 << 7);
    float t0 = b2[k2], t1 = 0.f, t2 = 0.f, t3 = 0.f;
    #pragma unroll
    for (int m = 0; m < DD; m += 4) {
      t0 = fmaf(s[m + 0], wc[m + 0], t0);
      t1 = fmaf(s[m + 1], wc[m + 1], t1);
      t2 = fmaf(s[m + 2], wc[m + 2], t2);
      t3 = fmaf(s[m + 3], wc[m + 3], t3);
    }
    acc3 = fmaf(siluf((t0 + t1) + (t2 + t3)), W3[k2], acc3);
  }
  out[e] = tanhf(acc3 + b3[0]);
}

// ---------------- launcher ----------------
extern "C" void kernel_launch(void* const* d_in, const int* in_sizes, int n_in,
                              void* d_out, int out_size, void* d_ws, size_t ws_size,
                              hipStream_t stream) {
  const float* x     = (const float*)d_in[0];
  const int*   ei    = (const int*)  d_in[1];
  const float* ea    = (const float*)d_in[2];
  const float* encW  = (const float*)d_in[4];
  const float* encb  = (const float*)d_in[5];
  const float* msgW  = (const float*)d_in[6];
  const float* msgb  = (const float*)d_in[7];
  const float* msgg  = (const float*)d_in[8];
  const float* msgbe = (const float*)d_in[9];
  const float* updW  = (const float*)d_in[10];
  const float* updb  = (const float*)d_in[11];
  const float* updg  = (const float*)d_in[12];
  const float* updbe = (const float*)d_in[13];
  const float* dW1   = (const float*)d_in[14];
  const float* db1   = (const float*)d_in[15];
  const float* dW2   = (const float*)d_in[16];
  const float* db2   = (const float*)d_in[17];
  const float* dW3   = (const float*)d_in[18];
  const float* db3   = (const float*)d_in[19];
  float* out = (float*)d_out;

  float* h     = (float*)d_ws;              // BN*DD
  float* adj   = h     + BN * DD;           // NB*NN*NN
  float* hT    = adj   + NB * NN * NN;      // BN*DD (t = h@Wt + mb; decoder P)
  float* hS    = hT    + BN * DD;           // BN*DD (s = h@Ws; decoder Q)
  float* agg   = hS    + BN * DD;           // BN*DD
  float* W2T   = agg   + BN * DD;           // 64*128
  float* statT = W2T   + 64 * DD;           // BN*4
  float* statS = statT + BN * 4;            // BN*4
  float* wst   = statS + BN * 4;            // 8
  float* MR    = wst   + 8;                 // NB*NN*NN*2 (rstd, -mean*rstd)

  hipMemsetAsync(adj, 0, (size_t)NB * NN * NN * sizeof(float), stream);
  k_encode<<<512, 256, 0, stream>>>(x, encW, encb, h);
  k_scatter<<<NE / 256, 256, 0, stream>>>(ei, ea, adj);
  k_wprep<<<NL, 64, 0, stream>>>(msgW, wst);

  for (int l = 0; l < NL; ++l) {
    const float* Wl = msgW + (size_t)l * (2 * DD + 1) * DD;
    const float* wjl = Wl + 2 * DD * DD;
    k_gemm2<<<BN / 8, 256, 0, stream>>>(h, Wl, Wl + DD * DD, msgb + l * DD, wjl,
                                        hT, hS, statT, statS);
    k_ts<<<256, 256, 0, stream>>>(hT, hS, adj, statT, statS, wst + 2 * l, MR);
    k_messages<<<512, 512, 0, stream>>>(hT, hS, MR, adj, wjl,
        msgg + l * DD, msgbe + l * DD, agg);
    k_update<<<BN / 8, 256, 0, stream>>>(h, agg, updW + (size_t)l * 2 * DD * DD,
        updb + l * DD, updg + l * DD, updbe + l * DD);
  }

  k_gemm2<<<BN / 8, 256, 0, stream>>>(h, dW1, dW1 + DD * DD, nullptr, nullptr,
                                      hT, hS, statT, statS);
  k_w2t<<<32, 256, 0, stream>>>(dW2, W2T);
  k_decoder<<<NE / 256, 256, 0, stream>>>(ei, ea, hT, hS, dW1 + 2 * DD * DD, db1,
      W2T, db2, dW3, db3, out);
}

// Round 4
// 328.672 us; speedup vs baseline: 1.8126x; 1.1781x over previous
//
#include <hip/hip_runtime.h>

#define NB 16
#define NN 256
#define DD 128
#define NL 3
#define NE 32768
#define BN 4096   // NB*NN

// ---------------- helpers ----------------
__device__ __forceinline__ float siluf(float y) {
  return __fdividef(y, 1.0f + __expf(-y));
}

template<int CTRL>
__device__ __forceinline__ float dpp_add(float x) {
  int v = __builtin_amdgcn_update_dpp(0, __float_as_int(x), CTRL, 0xF, 0xF, true);
  return x + __int_as_float(v);
}

// sum across 16-lane groups: quad xor1, xor2, half_mirror, mirror
__device__ __forceinline__ float sum16(float x) {
  x = dpp_add<0xB1>(x);
  x = dpp_add<0x4E>(x);
  x = dpp_add<0x141>(x);
  x = dpp_add<0x140>(x);
  return x;
}

// sum across 32 lanes (the two 32-halves reduce independently)
__device__ __forceinline__ float sum32(float x) {
  x = sum16(x);
  int v = __builtin_amdgcn_ds_swizzle(__float_as_int(x), 0x401F); // xor 16
  return x + __int_as_float(v);
}

__device__ __forceinline__ float sum64(float x) {
  x = sum32(x);
  return x + __shfl_xor(x, 32, 64);
}

// ---------------- kernels ----------------

__global__ __launch_bounds__(256) void k_encode(
    const float* __restrict__ x, const float* __restrict__ W,
    const float* __restrict__ bb, float* __restrict__ h) {
  int t = blockIdx.x * 256 + threadIdx.x;
  int i = t >> 5;
  int c = (t & 31) << 2;
  float xv = x[i];
  float4 w = *(const float4*)(W + c);
  float4 bv = *(const float4*)(bb + c);
  float4 o;
  o.x = fmaf(xv, w.x, bv.x); o.y = fmaf(xv, w.y, bv.y);
  o.z = fmaf(xv, w.z, bv.z); o.w = fmaf(xv, w.w, bv.w);
  *(float4*)(h + i * DD + c) = o;
}

__global__ __launch_bounds__(256) void k_scatter(
    const int* __restrict__ ei, const float* __restrict__ ea,
    float* __restrict__ adj) {
  int e = blockIdx.x * 256 + threadIdx.x;
  int g0 = ei[e];
  int g1 = ei[NE + e];
  float v = ea[e];
  int b = g0 >> 8;
  int s = g0 & 255;
  int d = g1 & 255;
  atomicAdd(adj + (b * NN + s) * NN + d, v);
  atomicAdd(adj + (b * NN + d) * NN + s, v);
}

// wstat[l] = (E[w], E[w^2]) for wj of layer l
__global__ __launch_bounds__(64) void k_wprep(
    const float* __restrict__ msgW, float* __restrict__ wst) {
  int l = blockIdx.x;
  const float* wj = msgW + (size_t)l * (2 * DD + 1) * DD + 2 * DD * DD;
  int d0 = threadIdx.x << 1;
  float2 wv = *(const float2*)(wj + d0);
  float s1 = sum64(wv.x + wv.y);
  float s2 = sum64(fmaf(wv.x, wv.x, wv.y * wv.y));
  if (threadIdx.x == 0)
    *(float2*)(wst + 2 * l) = make_float2(s1 * 0.0078125f, s2 * 0.0078125f);
}

// C1 = A@W1 (+bias1), C2 = A@W2; optional per-row stats vs wj.
__global__ __launch_bounds__(256) void k_gemm2(
    const float* __restrict__ A, const float* __restrict__ W1,
    const float* __restrict__ W2, const float* __restrict__ bias1,
    const float* __restrict__ wj,
    float* __restrict__ C1, float* __restrict__ C2,
    float* __restrict__ statT, float* __restrict__ statS) {
  __shared__ float sa[8][128];
  int r = threadIdx.x >> 5;
  int c4 = (threadIdx.x & 31) << 2;
  int row0 = blockIdx.x << 3;
  ((float4*)&sa[0][0])[threadIdx.x] = ((const float4*)(A + row0 * DD))[threadIdx.x];
  __syncthreads();
  float4 a1 = {0.f, 0.f, 0.f, 0.f}, a2 = {0.f, 0.f, 0.f, 0.f};
  #pragma unroll 4
  for (int m = 0; m < DD; ++m) {
    float a = sa[r][m];
    float4 w1 = *(const float4*)(W1 + m * DD + c4);
    float4 w2 = *(const float4*)(W2 + m * DD + c4);
    a1.x = fmaf(a, w1.x, a1.x); a1.y = fmaf(a, w1.y, a1.y);
    a1.z = fmaf(a, w1.z, a1.z); a1.w = fmaf(a, w1.w, a1.w);
    a2.x = fmaf(a, w2.x, a2.x); a2.y = fmaf(a, w2.y, a2.y);
    a2.z = fmaf(a, w2.z, a2.z); a2.w = fmaf(a, w2.w, a2.w);
  }
  if (bias1) {
    float4 bv = *(const float4*)(bias1 + c4);
    a1.x += bv.x; a1.y += bv.y; a1.z += bv.z; a1.w += bv.w;
  }
  int rw = row0 + r;
  *(float4*)(C1 + rw * DD + c4) = a1;
  *(float4*)(C2 + rw * DD + c4) = a2;
  if (wj) {
    float4 wv = *(const float4*)(wj + c4);
    float s1t = sum32((a1.x + a1.y) + (a1.z + a1.w));
    float s2t = sum32(fmaf(a1.x, a1.x, a1.y * a1.y) + fmaf(a1.z, a1.z, a1.w * a1.w));
    float s3t = sum32(fmaf(a1.x, wv.x, a1.y * wv.y) + fmaf(a1.z, wv.z, a1.w * wv.w));
    float s1s = sum32((a2.x + a2.y) + (a2.z + a2.w));
    float s2s = sum32(fmaf(a2.x, a2.x, a2.y * a2.y) + fmaf(a2.z, a2.z, a2.w * a2.w));
    float s3s = sum32(fmaf(a2.x, wv.x, a2.y * wv.y) + fmaf(a2.z, wv.z, a2.w * wv.w));
    if ((threadIdx.x & 31) == 0) {
      const float inv = 0.0078125f;
      ((float4*)statT)[rw] = make_float4(s1t * inv, s2t * inv, s3t * inv, 0.f);
      ((float4*)statS)[rw] = make_float4(s1s * inv, s2s * inv, s3s * inv, 0.f);
    }
  }
}

// TS GEMM + closed-form LN moments: MR[b,i,j] = (rstd, -mean*rstd)
__global__ __launch_bounds__(256) void k_ts(
    const float* __restrict__ T, const float* __restrict__ S,
    const float* __restrict__ adj,
    const float* __restrict__ statT, const float* __restrict__ statS,
    const float* __restrict__ wst, float* __restrict__ MR) {
  __shared__ float sT[64][64];  // k-major: sT[k][i]
  __shared__ float sS[64][64];
  int b = blockIdx.x >> 4;
  int i0 = ((blockIdx.x >> 2) & 3) << 6;
  int j0 = (blockIdx.x & 3) << 6;
  int t = threadIdx.x;
  int ti = t >> 4, tj = t & 15;
  float acc[4][4] = {};
  int sr = t >> 2, scg = t & 3;
  const float* Trow = T + ((size_t)(b * NN + i0 + sr)) * DD + scg * 16;
  const float* Srow = S + ((size_t)(b * NN + j0 + sr)) * DD + scg * 16;
  for (int kc = 0; kc < 2; ++kc) {
    __syncthreads();
    #pragma unroll
    for (int m = 0; m < 4; ++m) {
      float4 v = *(const float4*)(Trow + kc * 64 + m * 4);
      int kk = scg * 16 + m * 4;
      sT[kk + 0][sr] = v.x; sT[kk + 1][sr] = v.y;
      sT[kk + 2][sr] = v.z; sT[kk + 3][sr] = v.w;
      float4 u = *(const float4*)(Srow + kc * 64 + m * 4);
      sS[kk + 0][sr] = u.x; sS[kk + 1][sr] = u.y;
      sS[kk + 2][sr] = u.z; sS[kk + 3][sr] = u.w;
    }
    __syncthreads();
    #pragma unroll 4
    for (int k = 0; k < 64; ++k) {
      float4 rt = *(const float4*)&sT[k][ti << 2];
      float4 rs = *(const float4*)&sS[k][tj << 2];
      acc[0][0] = fmaf(rt.x, rs.x, acc[0][0]);
      acc[0][1] = fmaf(rt.x, rs.y, acc[0][1]);
      acc[0][2] = fmaf(rt.x, rs.z, acc[0][2]);
      acc[0][3] = fmaf(rt.x, rs.w, acc[0][3]);
      acc[1][0] = fmaf(rt.y, rs.x, acc[1][0]);
      acc[1][1] = fmaf(rt.y, rs.y, acc[1][1]);
      acc[1][2] = fmaf(rt.y, rs.z, acc[1][2]);
      acc[1][3] = fmaf(rt.y, rs.w, acc[1][3]);
      acc[2][0] = fmaf(rt.z, rs.x, acc[2][0]);
      acc[2][1] = fmaf(rt.z, rs.y, acc[2][1]);
      acc[2][2] = fmaf(rt.z, rs.z, acc[2][2]);
      acc[2][3] = fmaf(rt.z, rs.w, acc[2][3]);
      acc[3][0] = fmaf(rt.w, rs.x, acc[3][0]);
      acc[3][1] = fmaf(rt.w, rs.y, acc[3][1]);
      acc[3][2] = fmaf(rt.w, rs.z, acc[3][2]);
      acc[3][3] = fmaf(rt.w, rs.w, acc[3][3]);
    }
  }
  float2 ws = *(const float2*)wst;
  float4 stT[4], stS[4];
  #pragma unroll
  for (int o = 0; o < 4; ++o) {
    stT[o] = ((const float4*)statT)[b * NN + i0 + (ti << 2) + o];
    stS[o] = ((const float4*)statS)[b * NN + j0 + (tj << 2) + o];
  }
  #pragma unroll
  for (int oi = 0; oi < 4; ++oi) {
    int row = b * NN + i0 + (ti << 2) + oi;
    float4 av = *(const float4*)(adj + (size_t)row * NN + j0 + (tj << 2));
    float R[4], NMR[4];
    #pragma unroll
    for (int oj = 0; oj < 4; ++oj) {
      float a = (oj == 0) ? av.x : (oj == 1) ? av.y : (oj == 2) ? av.z : av.w;
      float mean = stT[oi].x + stS[oj].x + a * ws.x;
      float e2 = stT[oi].y + stS[oj].y + a * a * ws.y
               + fmaf(acc[oi][oj], 0.015625f, 2.f * a * (stT[oi].z + stS[oj].z));
      float var = fmaf(-mean, mean, e2);
      float Rv = rsqrtf(var + 1e-5f);
      R[oj] = Rv;
      NMR[oj] = -mean * Rv;
    }
    float2* mrow = (float2*)MR + (size_t)row * NN + j0 + (tj << 2);
    *(float4*)(mrow)     = make_float4(R[0], NMR[0], R[1], NMR[1]);
    *(float4*)(mrow + 2) = make_float4(R[2], NMR[2], R[3], NMR[3]);
  }
}

// messages + aggregation: 8 waves/block, wave-per-i, register-prefetch dbuf
__global__ __launch_bounds__(512, 4) void k_messages(
    const float* __restrict__ hT, const float* __restrict__ hS,
    const float* __restrict__ MR, const float* __restrict__ adj,
    const float* __restrict__ wj, const float* __restrict__ mg,
    const float* __restrict__ mbe, float* __restrict__ agg) {
  __shared__ float sh[64 * 128];     // 32 KB: current 64-row chunk of hS
  __shared__ float sadj[8 * 256];    // 8 KB: adj rows for this block's 8 i's
  __shared__ float smr[8 * 64 * 2];  // 4 KB: (rstd, nmr) for current chunk
  const float LN2 = 0.6931471805599453f;
  const float L2E = 1.4426950408889634f;
  int b = blockIdx.x >> 5;
  int i0 = (blockIdx.x & 31) << 3;
  int t = threadIdx.x;
  ((float4*)sadj)[t] = ((const float4*)(adj + (size_t)(b * NN + i0) * NN))[t];

  int w = t >> 6, lane = t & 63;
  int i = i0 + w, row = b * NN + i;
  int d0 = lane << 1;
  float2 tv = *(const float2*)(hT + (size_t)row * DD + d0);  // includes mb
  float2 wv = *(const float2*)(wj + d0);
  float2 gv = *(const float2*)(mg + d0);
  float2 bev = *(const float2*)(mbe + d0);
  float G0 = gv.x * L2E, G1 = gv.y * L2E;
  float BE0 = bev.x * L2E, BE1 = bev.y * L2E;
  float acc0 = 0.f, acc1 = 0.f;

  const float4* hsrc = (const float4*)(hS + (size_t)(b * NN) * DD);
  const float2* mrsrc = (const float2*)MR + (size_t)(b * NN + i0 + (t >> 6)) * NN + (t & 63);

  float4 p0 = hsrc[t], p1 = hsrc[t + 512], p2 = hsrc[t + 1024], p3 = hsrc[t + 1536];
  float2 pm = mrsrc[0];
  ((float4*)sh)[t] = p0; ((float4*)sh)[t + 512] = p1;
  ((float4*)sh)[t + 1024] = p2; ((float4*)sh)[t + 1536] = p3;
  ((float2*)smr)[t] = pm;
  __syncthreads();

  const float* arowb = sadj + w * NN;
  const float2* mrw = (const float2*)smr + w * 64;

  for (int c = 0; c < 4; ++c) {
    if (c < 3) {
      const float4* hn = hsrc + (c + 1) * 2048;
      p0 = hn[t]; p1 = hn[t + 512]; p2 = hn[t + 1024]; p3 = hn[t + 1536];
      pm = mrsrc[(c + 1) * 64];
    }
    const float* arow = arowb + c * 64;
    #pragma unroll 4
    for (int jj = 0; jj < 64; ++jj) {
      float2 mr = mrw[jj];
      float a = arow[jj];
      float2 hs = *(const float2*)(sh + jj * DD + d0);
      float v0 = tv.x + hs.x; v0 = fmaf(a, wv.x, v0);
      float v1 = tv.y + hs.y; v1 = fmaf(a, wv.y, v1);
      float z0 = fmaf(mr.x, v0, mr.y);
      float z1 = fmaf(mr.x, v1, mr.y);
      float yl0 = fmaf(G0, z0, BE0);
      float yl1 = fmaf(G1, z1, BE1);
      float e0 = __builtin_amdgcn_exp2f(-yl0);
      float e1 = __builtin_amdgcn_exp2f(-yl1);
      float den0 = 1.0f + e0, den1 = 1.0f + e1;
      float r = __builtin_amdgcn_rcpf(den0 * den1);
      acc0 = fmaf((yl0 * den1) * r, LN2, acc0);
      acc1 = fmaf((yl1 * den0) * r, LN2, acc1);
    }
    if ((i >> 6) == c) {
      int li = i & 63;
      float2 mr = mrw[li];
      float a = arow[li];
      float2 hs = *(const float2*)(sh + li * DD + d0);
      float v0 = tv.x + hs.x; v0 = fmaf(a, wv.x, v0);
      float v1 = tv.y + hs.y; v1 = fmaf(a, wv.y, v1);
      float z0 = fmaf(mr.x, v0, mr.y);
      float z1 = fmaf(mr.x, v1, mr.y);
      float yl0 = fmaf(G0, z0, BE0);
      float yl1 = fmaf(G1, z1, BE1);
      float e0 = __builtin_amdgcn_exp2f(-yl0);
      float e1 = __builtin_amdgcn_exp2f(-yl1);
      float den0 = 1.0f + e0, den1 = 1.0f + e1;
      float r = __builtin_amdgcn_rcpf(den0 * den1);
      acc0 = fmaf((yl0 * den1) * r, -LN2, acc0);
      acc1 = fmaf((yl1 * den0) * r, -LN2, acc1);
    }
    __syncthreads();
    if (c < 3) {
      ((float4*)sh)[t] = p0; ((float4*)sh)[t + 512] = p1;
      ((float4*)sh)[t + 1024] = p2; ((float4*)sh)[t + 1536] = p3;
      ((float2*)smr)[t] = pm;
      __syncthreads();
    }
  }
  *(float2*)(agg + (size_t)row * DD + d0) = make_float2(acc0, acc1);
}

// u = [h|agg] @ W + ub;  h += silu(LN(u))
__global__ __launch_bounds__(256) void k_update(
    float* __restrict__ h, const float* __restrict__ agg,
    const float* __restrict__ W, const float* __restrict__ ub,
    const float* __restrict__ ug, const float* __restrict__ ube) {
  __shared__ float scat[8][256];
  int r = threadIdx.x >> 5;
  int c4 = (threadIdx.x & 31) << 2;
  int row0 = blockIdx.x << 3;
  {
    int t = threadIdx.x;
    float4 v = ((const float4*)(h + row0 * DD))[t];
    int f = t << 2; int rr = f >> 7; int mm = f & 127;
    *(float4*)&scat[rr][mm] = v;
    float4 va = ((const float4*)(agg + row0 * DD))[t];
    *(float4*)&scat[rr][DD + mm] = va;
  }
  __syncthreads();
  float4 acc = *(const float4*)(ub + c4);
  #pragma unroll 4
  for (int m = 0; m < 2 * DD; ++m) {
    float a = scat[r][m];
    float4 wv = *(const float4*)(W + m * DD + c4);
    acc.x = fmaf(a, wv.x, acc.x);
    acc.y = fmaf(a, wv.y, acc.y);
    acc.z = fmaf(a, wv.z, acc.z);
    acc.w = fmaf(a, wv.w, acc.w);
  }
  float s1 = sum32((acc.x + acc.y) + (acc.z + acc.w));
  float s2 = sum32(fmaf(acc.x, acc.x, acc.y * acc.y) + fmaf(acc.z, acc.z, acc.w * acc.w));
  float mean = s1 * 0.0078125f;
  float var = fmaf(-mean, mean, s2 * 0.0078125f);
  float rstd = rsqrtf(var + 1e-5f);
  float4 g  = *(const float4*)(ug + c4);
  float4 be = *(const float4*)(ube + c4);
  float4 ho = *(const float4*)&scat[r][c4];
  float4 o;
  o.x = ho.x + siluf(fmaf((acc.x - mean) * rstd, g.x, be.x));
  o.y = ho.y + siluf(fmaf((acc.y - mean) * rstd, g.y, be.y));
  o.z = ho.z + siluf(fmaf((acc.z - mean) * rstd, g.z, be.z));
  o.w = ho.w + siluf(fmaf((acc.w - mean) * rstd, g.w, be.w));
  *(float4*)(h + (row0 + r) * DD + c4) = o;
}

// decoder: 64 edges/block tiled GEMM. Phase1: gather+silu into LDS.
// Phase2: 16x16 threads, 4 edges x 4 k2 each, W2 from global (L1-resident).
// Phase3: silu(+b2) dot W3, 16-lane DPP reduce, tanh.
__global__ __launch_bounds__(256, 2) void k_decoder(
    const int* __restrict__ ei, const float* __restrict__ ea,
    const float* __restrict__ P, const float* __restrict__ Q,
    const float* __restrict__ w1e, const float* __restrict__ b1,
    const float* __restrict__ W2, const float* __restrict__ b2,
    const float* __restrict__ W3, const float* __restrict__ b3,
    float* __restrict__ out) {
  __shared__ float sS[64][132];   // stride 132: 16B-aligned float4 rows, low conflicts
  int t = threadIdx.x;
  {
    int e = t >> 2, qq = t & 3;           // 4 threads per edge, 32 d's each
    int eg = (blockIdx.x << 6) + e;
    int g0 = ei[eg], g1 = ei[NE + eg];
    float av = ea[eg];
    const float4* p4 = (const float4*)(P + (size_t)g0 * DD + qq * 32);
    const float4* q4 = (const float4*)(Q + (size_t)g1 * DD + qq * 32);
    const float4* w4 = (const float4*)(w1e + qq * 32);
    const float4* b4 = (const float4*)(b1 + qq * 32);
    #pragma unroll
    for (int m = 0; m < 8; ++m) {
      float4 p = p4[m], qv = q4[m], wv = w4[m], bv = b4[m];
      float4 sv;
      sv.x = siluf(fmaf(av, wv.x, (p.x + qv.x) + bv.x));
      sv.y = siluf(fmaf(av, wv.y, (p.y + qv.y) + bv.y));
      sv.z = siluf(fmaf(av, wv.z, (p.z + qv.z) + bv.z));
      sv.w = siluf(fmaf(av, wv.w, (p.w + qv.w) + bv.w));
      *(float4*)&sS[e][(qq << 5) + (m << 2)] = sv;
    }
  }
  __syncthreads();
  int ti = t >> 4, tj = t & 15;   // edge-group ti*4.., k2-group tj*4..
  float4 acc[4] = {{0.f,0.f,0.f,0.f},{0.f,0.f,0.f,0.f},{0.f,0.f,0.f,0.f},{0.f,0.f,0.f,0.f}};
  const float4* W2g = (const float4*)W2;  // [128][16 float4]
  #pragma unroll 4
  for (int k4 = 0; k4 < 32; ++k4) {
    float4 sv[4], wv[4];
    #pragma unroll
    for (int r = 0; r < 4; ++r)
      sv[r] = *(const float4*)&sS[(ti << 2) + r][k4 << 2];
    #pragma unroll
    for (int kk = 0; kk < 4; ++kk)
      wv[kk] = W2g[(((k4 << 2) + kk) << 4) + tj];
    #pragma unroll
    for (int r = 0; r < 4; ++r) {
      acc[r].x = fmaf(sv[r].x, wv[0].x, acc[r].x);
      acc[r].y = fmaf(sv[r].x, wv[0].y, acc[r].y);
      acc[r].z = fmaf(sv[r].x, wv[0].z, acc[r].z);
      acc[r].w = fmaf(sv[r].x, wv[0].w, acc[r].w);
      acc[r].x = fmaf(sv[r].y, wv[1].x, acc[r].x);
      acc[r].y = fmaf(sv[r].y, wv[1].y, acc[r].y);
      acc[r].z = fmaf(sv[r].y, wv[1].z, acc[r].z);
      acc[r].w = fmaf(sv[r].y, wv[1].w, acc[r].w);
      acc[r].x = fmaf(sv[r].z, wv[2].x, acc[r].x);
      acc[r].y = fmaf(sv[r].z, wv[2].y, acc[r].y);
      acc[r].z = fmaf(sv[r].z, wv[2].z, acc[r].z);
      acc[r].w = fmaf(sv[r].z, wv[2].w, acc[r].w);
      acc[r].x = fmaf(sv[r].w, wv[3].x, acc[r].x);
      acc[r].y = fmaf(sv[r].w, wv[3].y, acc[r].y);
      acc[r].z = fmaf(sv[r].w, wv[3].z, acc[r].z);
      acc[r].w = fmaf(sv[r].w, wv[3].w, acc[r].w);
    }
  }
  float4 b2v = *(const float4*)(b2 + (tj << 2));
  float4 w3v = *(const float4*)(W3 + (tj << 2));
  float b3v = b3[0];
  #pragma unroll
  for (int r = 0; r < 4; ++r) {
    float part = siluf(acc[r].x + b2v.x) * w3v.x;
    part = fmaf(siluf(acc[r].y + b2v.y), w3v.y, part);
    part = fmaf(siluf(acc[r].z + b2v.z), w3v.z, part);
    part = fmaf(siluf(acc[r].w + b2v.w), w3v.w, part);
    part = sum16(part);
    if (tj == 0)
      out[(blockIdx.x << 6) + (ti << 2) + r] = tanhf(part + b3v);
  }
}

// ---------------- launcher ----------------
extern "C" void kernel_launch(void* const* d_in, const int* in_sizes, int n_in,
                              void* d_out, int out_size, void* d_ws, size_t ws_size,
                              hipStream_t stream) {
  const float* x     = (const float*)d_in[0];
  const int*   ei    = (const int*)  d_in[1];
  const float* ea    = (const float*)d_in[2];
  const float* encW  = (const float*)d_in[4];
  const float* encb  = (const float*)d_in[5];
  const float* msgW  = (const float*)d_in[6];
  const float* msgb  = (const float*)d_in[7];
  const float* msgg  = (const float*)d_in[8];
  const float* msgbe = (const float*)d_in[9];
  const float* updW  = (const float*)d_in[10];
  const float* updb  = (const float*)d_in[11];
  const float* updg  = (const float*)d_in[12];
  const float* updbe = (const float*)d_in[13];
  const float* dW1   = (const float*)d_in[14];
  const float* db1   = (const float*)d_in[15];
  const float* dW2   = (const float*)d_in[16];
  const float* db2   = (const float*)d_in[17];
  const float* dW3   = (const float*)d_in[18];
  const float* db3   = (const float*)d_in[19];
  float* out = (float*)d_out;

  float* h     = (float*)d_ws;              // BN*DD
  float* adj   = h     + BN * DD;           // NB*NN*NN
  float* hT    = adj   + NB * NN * NN;      // BN*DD (t = h@Wt + mb; decoder P)
  float* hS    = hT    + BN * DD;           // BN*DD (s = h@Ws; decoder Q)
  float* agg   = hS    + BN * DD;           // BN*DD
  float* W2T   = agg   + BN * DD;           // (unused)
  float* statT = W2T   + 64 * DD;           // BN*4
  float* statS = statT + BN * 4;            // BN*4
  float* wst   = statS + BN * 4;            // 8
  float* MR    = wst   + 8;                 // NB*NN*NN*2 (rstd, -mean*rstd)

  hipMemsetAsync(adj, 0, (size_t)NB * NN * NN * sizeof(float), stream);
  k_encode<<<512, 256, 0, stream>>>(x, encW, encb, h);
  k_scatter<<<NE / 256, 256, 0, stream>>>(ei, ea, adj);
  k_wprep<<<NL, 64, 0, stream>>>(msgW, wst);

  for (int l = 0; l < NL; ++l) {
    const float* Wl = msgW + (size_t)l * (2 * DD + 1) * DD;
    const float* wjl = Wl + 2 * DD * DD;
    k_gemm2<<<BN / 8, 256, 0, stream>>>(h, Wl, Wl + DD * DD, msgb + l * DD, wjl,
                                        hT, hS, statT, statS);
    k_ts<<<256, 256, 0, stream>>>(hT, hS, adj, statT, statS, wst + 2 * l, MR);
    k_messages<<<512, 512, 0, stream>>>(hT, hS, MR, adj, wjl,
        msgg + l * DD, msgbe + l * DD, agg);
    k_update<<<BN / 8, 256, 0, stream>>>(h, agg, updW + (size_t)l * 2 * DD * DD,
        updb + l * DD, updg + l * DD, updbe + l * DD);
  }

  k_gemm2<<<BN / 8, 256, 0, stream>>>(h, dW1, dW1 + DD * DD, nullptr, nullptr,
                                      hT, hS, statT, statS);
  k_decoder<<<NE / 64, 256, 0, stream>>>(ei, ea, hT, hS, dW1 + 2 * DD * DD, db1,
      dW2, db2, dW3, db3, out);
}

// Round 5
// 327.192 us; speedup vs baseline: 1.8208x; 1.0045x over previous
//
#include <hip/hip_runtime.h>

#define NB 16
#define NN 256
#define DD 128
#define NL 3
#define NE 32768
#define BN 4096   // NB*NN

// ---------------- helpers ----------------
__device__ __forceinline__ float siluf(float y) {
  return __fdividef(y, 1.0f + __expf(-y));
}

template<int CTRL>
__device__ __forceinline__ float dpp_add(float x) {
  int v = __builtin_amdgcn_update_dpp(0, __float_as_int(x), CTRL, 0xF, 0xF, true);
  return x + __int_as_float(v);
}

// sum across 16-lane groups
__device__ __forceinline__ float sum16(float x) {
  x = dpp_add<0xB1>(x);
  x = dpp_add<0x4E>(x);
  x = dpp_add<0x141>(x);
  x = dpp_add<0x140>(x);
  return x;
}

__device__ __forceinline__ float sum32(float x) {
  x = sum16(x);
  int v = __builtin_amdgcn_ds_swizzle(__float_as_int(x), 0x401F); // xor 16
  return x + __int_as_float(v);
}

__device__ __forceinline__ float sum64(float x) {
  x = sum32(x);
  return x + __shfl_xor(x, 32, 64);
}

// ---------------- kernels ----------------

__global__ __launch_bounds__(256) void k_encode(
    const float* __restrict__ x, const float* __restrict__ W,
    const float* __restrict__ bb, float* __restrict__ h) {
  int t = blockIdx.x * 256 + threadIdx.x;
  int i = t >> 5;
  int c = (t & 31) << 2;
  float xv = x[i];
  float4 w = *(const float4*)(W + c);
  float4 bv = *(const float4*)(bb + c);
  float4 o;
  o.x = fmaf(xv, w.x, bv.x); o.y = fmaf(xv, w.y, bv.y);
  o.z = fmaf(xv, w.z, bv.z); o.w = fmaf(xv, w.w, bv.w);
  *(float4*)(h + i * DD + c) = o;
}

__global__ __launch_bounds__(256) void k_scatter(
    const int* __restrict__ ei, const float* __restrict__ ea,
    float* __restrict__ adj) {
  int e = blockIdx.x * 256 + threadIdx.x;
  int g0 = ei[e];
  int g1 = ei[NE + e];
  float v = ea[e];
  int b = g0 >> 8;
  int s = g0 & 255;
  int d = g1 & 255;
  atomicAdd(adj + (b * NN + s) * NN + d, v);
  atomicAdd(adj + (b * NN + d) * NN + s, v);
}

// wstat[l] = (E[w], E[w^2]) for wj of layer l
__global__ __launch_bounds__(64) void k_wprep(
    const float* __restrict__ msgW, float* __restrict__ wst) {
  int l = blockIdx.x;
  const float* wj = msgW + (size_t)l * (2 * DD + 1) * DD + 2 * DD * DD;
  int d0 = threadIdx.x << 1;
  float2 wv = *(const float2*)(wj + d0);
  float s1 = sum64(wv.x + wv.y);
  float s2 = sum64(fmaf(wv.x, wv.x, wv.y * wv.y));
  if (threadIdx.x == 0)
    *(float2*)(wst + 2 * l) = make_float2(s1 * 0.0078125f, s2 * 0.0078125f);
}

// C1 = A@W1 (+bias1), C2 = A@W2; optional per-row stats vs wj.
__global__ __launch_bounds__(256) void k_gemm2(
    const float* __restrict__ A, const float* __restrict__ W1,
    const float* __restrict__ W2, const float* __restrict__ bias1,
    const float* __restrict__ wj,
    float* __restrict__ C1, float* __restrict__ C2,
    float* __restrict__ statT, float* __restrict__ statS) {
  __shared__ float sa[8][128];
  int r = threadIdx.x >> 5;
  int c4 = (threadIdx.x & 31) << 2;
  int row0 = blockIdx.x << 3;
  ((float4*)&sa[0][0])[threadIdx.x] = ((const float4*)(A + row0 * DD))[threadIdx.x];
  __syncthreads();
  float4 a1 = {0.f, 0.f, 0.f, 0.f}, a2 = {0.f, 0.f, 0.f, 0.f};
  #pragma unroll 4
  for (int m = 0; m < DD; ++m) {
    float a = sa[r][m];
    float4 w1 = *(const float4*)(W1 + m * DD + c4);
    float4 w2 = *(const float4*)(W2 + m * DD + c4);
    a1.x = fmaf(a, w1.x, a1.x); a1.y = fmaf(a, w1.y, a1.y);
    a1.z = fmaf(a, w1.z, a1.z); a1.w = fmaf(a, w1.w, a1.w);
    a2.x = fmaf(a, w2.x, a2.x); a2.y = fmaf(a, w2.y, a2.y);
    a2.z = fmaf(a, w2.z, a2.z); a2.w = fmaf(a, w2.w, a2.w);
  }
  if (bias1) {
    float4 bv = *(const float4*)(bias1 + c4);
    a1.x += bv.x; a1.y += bv.y; a1.z += bv.z; a1.w += bv.w;
  }
  int rw = row0 + r;
  *(float4*)(C1 + rw * DD + c4) = a1;
  *(float4*)(C2 + rw * DD + c4) = a2;
  if (wj) {
    float4 wv = *(const float4*)(wj + c4);
    float s1t = sum32((a1.x + a1.y) + (a1.z + a1.w));
    float s2t = sum32(fmaf(a1.x, a1.x, a1.y * a1.y) + fmaf(a1.z, a1.z, a1.w * a1.w));
    float s3t = sum32(fmaf(a1.x, wv.x, a1.y * wv.y) + fmaf(a1.z, wv.z, a1.w * wv.w));
    float s1s = sum32((a2.x + a2.y) + (a2.z + a2.w));
    float s2s = sum32(fmaf(a2.x, a2.x, a2.y * a2.y) + fmaf(a2.z, a2.z, a2.w * a2.w));
    float s3s = sum32(fmaf(a2.x, wv.x, a2.y * wv.y) + fmaf(a2.z, wv.z, a2.w * wv.w));
    if ((threadIdx.x & 31) == 0) {
      const float inv = 0.0078125f;
      ((float4*)statT)[rw] = make_float4(s1t * inv, s2t * inv, s3t * inv, 0.f);
      ((float4*)statS)[rw] = make_float4(s1s * inv, s2s * inv, s3s * inv, 0.f);
    }
  }
}

// TS GEMM + closed-form LN moments: MR4[b,i,j] = (rstd, -mean*rstd, a, 0)
__global__ __launch_bounds__(256) void k_ts(
    const float* __restrict__ T, const float* __restrict__ S,
    const float* __restrict__ adj,
    const float* __restrict__ statT, const float* __restrict__ statS,
    const float* __restrict__ wst, float* __restrict__ MR4) {
  __shared__ float sT[64][64];  // k-major: sT[k][i]
  __shared__ float sS[64][64];
  int b = blockIdx.x >> 4;
  int i0 = ((blockIdx.x >> 2) & 3) << 6;
  int j0 = (blockIdx.x & 3) << 6;
  int t = threadIdx.x;
  int ti = t >> 4, tj = t & 15;
  float acc[4][4] = {};
  int sr = t >> 2, scg = t & 3;
  const float* Trow = T + ((size_t)(b * NN + i0 + sr)) * DD + scg * 16;
  const float* Srow = S + ((size_t)(b * NN + j0 + sr)) * DD + scg * 16;
  for (int kc = 0; kc < 2; ++kc) {
    __syncthreads();
    #pragma unroll
    for (int m = 0; m < 4; ++m) {
      float4 v = *(const float4*)(Trow + kc * 64 + m * 4);
      int kk = scg * 16 + m * 4;
      sT[kk + 0][sr] = v.x; sT[kk + 1][sr] = v.y;
      sT[kk + 2][sr] = v.z; sT[kk + 3][sr] = v.w;
      float4 u = *(const float4*)(Srow + kc * 64 + m * 4);
      sS[kk + 0][sr] = u.x; sS[kk + 1][sr] = u.y;
      sS[kk + 2][sr] = u.z; sS[kk + 3][sr] = u.w;
    }
    __syncthreads();
    #pragma unroll 4
    for (int k = 0; k < 64; ++k) {
      float4 rt = *(const float4*)&sT[k][ti << 2];
      float4 rs = *(const float4*)&sS[k][tj << 2];
      acc[0][0] = fmaf(rt.x, rs.x, acc[0][0]);
      acc[0][1] = fmaf(rt.x, rs.y, acc[0][1]);
      acc[0][2] = fmaf(rt.x, rs.z, acc[0][2]);
      acc[0][3] = fmaf(rt.x, rs.w, acc[0][3]);
      acc[1][0] = fmaf(rt.y, rs.x, acc[1][0]);
      acc[1][1] = fmaf(rt.y, rs.y, acc[1][1]);
      acc[1][2] = fmaf(rt.y, rs.z, acc[1][2]);
      acc[1][3] = fmaf(rt.y, rs.w, acc[1][3]);
      acc[2][0] = fmaf(rt.z, rs.x, acc[2][0]);
      acc[2][1] = fmaf(rt.z, rs.y, acc[2][1]);
      acc[2][2] = fmaf(rt.z, rs.z, acc[2][2]);
      acc[2][3] = fmaf(rt.z, rs.w, acc[2][3]);
      acc[3][0] = fmaf(rt.w, rs.x, acc[3][0]);
      acc[3][1] = fmaf(rt.w, rs.y, acc[3][1]);
      acc[3][2] = fmaf(rt.w, rs.z, acc[3][2]);
      acc[3][3] = fmaf(rt.w, rs.w, acc[3][3]);
    }
  }
  float2 ws = *(const float2*)wst;
  float4 stT[4], stS[4];
  #pragma unroll
  for (int o = 0; o < 4; ++o) {
    stT[o] = ((const float4*)statT)[b * NN + i0 + (ti << 2) + o];
    stS[o] = ((const float4*)statS)[b * NN + j0 + (tj << 2) + o];
  }
  #pragma unroll
  for (int oi = 0; oi < 4; ++oi) {
    int row = b * NN + i0 + (ti << 2) + oi;
    float4 av = *(const float4*)(adj + (size_t)row * NN + j0 + (tj << 2));
    float4* m4row = (float4*)MR4 + (size_t)row * NN + j0 + (tj << 2);
    #pragma unroll
    for (int oj = 0; oj < 4; ++oj) {
      float a = (oj == 0) ? av.x : (oj == 1) ? av.y : (oj == 2) ? av.z : av.w;
      float mean = stT[oi].x + stS[oj].x + a * ws.x;
      float e2 = stT[oi].y + stS[oj].y + a * a * ws.y
               + fmaf(acc[oi][oj], 0.015625f, 2.f * a * (stT[oi].z + stS[oj].z));
      float var = fmaf(-mean, mean, e2);
      float Rv = rsqrtf(var + 1e-5f);
      m4row[oj] = make_float4(Rv, -mean * Rv, a, 0.f);
    }
  }
}

// messages + aggregation: 8 waves = 4 i x 2 j-halves, register-prefetch dbuf
__global__ __launch_bounds__(512, 6) void k_messages(
    const float* __restrict__ hT, const float* __restrict__ hS,
    const float* __restrict__ MR4, const float* __restrict__ wj,
    const float* __restrict__ mg, const float* __restrict__ mbe,
    float* __restrict__ agg) {
  __shared__ float sh[64 * 128];   // 32 KB: current 64-row chunk of hS
  __shared__ float4 smr[256];      // 4 KB: (rstd, nmr, a) for 4 i x 64 j
  const float LN2 = 0.6931471805599453f;
  const float L2E = 1.4426950408889634f;
  int b = blockIdx.x >> 6;
  int i0 = (blockIdx.x & 63) << 2;
  int t = threadIdx.x;
  int w = t >> 6, lane = t & 63;
  int il = w >> 1, jh = w & 1, jb = jh << 5;
  int i = i0 + il, row = b * NN + i;
  int d0 = lane << 1;
  float2 tv = *(const float2*)(hT + (size_t)row * DD + d0);  // includes mb
  float2 wv = *(const float2*)(wj + d0);
  float2 gv = *(const float2*)(mg + d0);
  float2 bev = *(const float2*)(mbe + d0);
  float G0 = gv.x * L2E, G1 = gv.y * L2E;
  float BE0 = bev.x * L2E, BE1 = bev.y * L2E;
  float acc0 = 0.f, acc1 = 0.f;

  const float4* hsrc = (const float4*)(hS + (size_t)(b * NN) * DD);
  // MR4 rows for this block's 4 i's; threads 0..255 (waves 0-3) stage them.
  int ml = t >> 6, mj = t & 63;  // valid when t < 256
  const float4* msrc = (const float4*)MR4 + (size_t)(b * NN + i0 + ml) * NN + mj;

  // prefetch chunk 0
  float4 p0 = hsrc[t], p1 = hsrc[t + 512], p2 = hsrc[t + 1024], p3 = hsrc[t + 1536];
  float4 pm;
  if (t < 256) pm = msrc[0];
  ((float4*)sh)[t] = p0; ((float4*)sh)[t + 512] = p1;
  ((float4*)sh)[t + 1024] = p2; ((float4*)sh)[t + 1536] = p3;
  if (t < 256) smr[t] = pm;
  __syncthreads();

  const float4* mrw = smr + (il << 6) + jb;

  for (int c = 0; c < 4; ++c) {
    if (c < 3) {  // issue next-chunk loads; stay in flight across compute
      const float4* hn = hsrc + (c + 1) * 2048;
      p0 = hn[t]; p1 = hn[t + 512]; p2 = hn[t + 1024]; p3 = hn[t + 1536];
      if (t < 256) pm = msrc[(c + 1) * 64];
    }
    #pragma unroll 4
    for (int jj = 0; jj < 32; ++jj) {
      float4 m4 = mrw[jj];
      float2 hs = *(const float2*)(sh + ((jb + jj) << 7) + d0);
      float v0 = tv.x + hs.x; v0 = fmaf(m4.z, wv.x, v0);
      float v1 = tv.y + hs.y; v1 = fmaf(m4.z, wv.y, v1);
      float z0 = fmaf(m4.x, v0, m4.y);
      float z1 = fmaf(m4.x, v1, m4.y);
      float yl0 = fmaf(G0, z0, BE0);
      float yl1 = fmaf(G1, z1, BE1);
      float e0 = __builtin_amdgcn_exp2f(-yl0);
      float e1 = __builtin_amdgcn_exp2f(-yl1);
      float den0 = 1.0f + e0, den1 = 1.0f + e1;
      float r = __builtin_amdgcn_rcpf(den0 * den1);
      acc0 = fmaf(yl0 * den1, r, acc0);
      acc1 = fmaf(yl1 * den0, r, acc1);
    }
    if ((i >> 6) == c && ((i >> 5) & 1) == jh) {  // subtract j == i (wave-uniform)
      int li = i & 31;
      float4 m4 = mrw[li];
      float2 hs = *(const float2*)(sh + ((jb + li) << 7) + d0);
      float v0 = tv.x + hs.x; v0 = fmaf(m4.z, wv.x, v0);
      float v1 = tv.y + hs.y; v1 = fmaf(m4.z, wv.y, v1);
      float z0 = fmaf(m4.x, v0, m4.y);
      float z1 = fmaf(m4.x, v1, m4.y);
      float yl0 = fmaf(G0, z0, BE0);
      float yl1 = fmaf(G1, z1, BE1);
      float e0 = __builtin_amdgcn_exp2f(-yl0);
      float e1 = __builtin_amdgcn_exp2f(-yl1);
      float den0 = 1.0f + e0, den1 = 1.0f + e1;
      float r = __builtin_amdgcn_rcpf(den0 * den1);
      acc0 = fmaf(yl0 * den1, -r, acc0);
      acc1 = fmaf(yl1 * den0, -r, acc1);
    }
    __syncthreads();
    if (c < 3) {
      ((float4*)sh)[t] = p0; ((float4*)sh)[t + 512] = p1;
      ((float4*)sh)[t + 1024] = p2; ((float4*)sh)[t + 1536] = p3;
      if (t < 256) smr[t] = pm;
      __syncthreads();
    }
  }
  // merge the two j-halves of each i via LDS (reuse smr as float2 buffer)
  if (jh == 1)
    ((float2*)smr)[(il << 6) + lane] = make_float2(acc0, acc1);
  __syncthreads();
  if (jh == 0) {
    float2 o = ((float2*)smr)[(il << 6) + lane];
    acc0 += o.x; acc1 += o.y;
    *(float2*)(agg + (size_t)row * DD + d0) =
        make_float2(acc0 * LN2, acc1 * LN2);
  }
}

// u = [h|agg] @ W + ub;  h += silu(LN(u))
__global__ __launch_bounds__(256) void k_update(
    float* __restrict__ h, const float* __restrict__ agg,
    const float* __restrict__ W, const float* __restrict__ ub,
    const float* __restrict__ ug, const float* __restrict__ ube) {
  __shared__ float scat[8][256];
  int r = threadIdx.x >> 5;
  int c4 = (threadIdx.x & 31) << 2;
  int row0 = blockIdx.x << 3;
  {
    int t = threadIdx.x;
    float4 v = ((const float4*)(h + row0 * DD))[t];
    int f = t << 2; int rr = f >> 7; int mm = f & 127;
    *(float4*)&scat[rr][mm] = v;
    float4 va = ((const float4*)(agg + row0 * DD))[t];
    *(float4*)&scat[rr][DD + mm] = va;
  }
  __syncthreads();
  float4 acc = *(const float4*)(ub + c4);
  #pragma unroll 4
  for (int m = 0; m < 2 * DD; ++m) {
    float a = scat[r][m];
    float4 wv = *(const float4*)(W + m * DD + c4);
    acc.x = fmaf(a, wv.x, acc.x);
    acc.y = fmaf(a, wv.y, acc.y);
    acc.z = fmaf(a, wv.z, acc.z);
    acc.w = fmaf(a, wv.w, acc.w);
  }
  float s1 = sum32((acc.x + acc.y) + (acc.z + acc.w));
  float s2 = sum32(fmaf(acc.x, acc.x, acc.y * acc.y) + fmaf(acc.z, acc.z, acc.w * acc.w));
  float mean = s1 * 0.0078125f;
  float var = fmaf(-mean, mean, s2 * 0.0078125f);
  float rstd = rsqrtf(var + 1e-5f);
  float4 g  = *(const float4*)(ug + c4);
  float4 be = *(const float4*)(ube + c4);
  float4 ho = *(const float4*)&scat[r][c4];
  float4 o;
  o.x = ho.x + siluf(fmaf((acc.x - mean) * rstd, g.x, be.x));
  o.y = ho.y + siluf(fmaf((acc.y - mean) * rstd, g.y, be.y));
  o.z = ho.z + siluf(fmaf((acc.z - mean) * rstd, g.z, be.z));
  o.w = ho.w + siluf(fmaf((acc.w - mean) * rstd, g.w, be.w));
  *(float4*)(h + (row0 + r) * DD + c4) = o;
}

// decoder: 64 edges/block tiled GEMM. Phase1: gather+silu into LDS.
// Phase2: 16x16 threads, 4 edges x 4 k2 each, W2 from global (L1-resident).
// Phase3: silu(+b2) dot W3, 16-lane DPP reduce, tanh.
__global__ __launch_bounds__(256, 2) void k_decoder(
    const int* __restrict__ ei, const float* __restrict__ ea,
    const float* __restrict__ P, const float* __restrict__ Q,
    const float* __restrict__ w1e, const float* __restrict__ b1,
    const float* __restrict__ W2, const float* __restrict__ b2,
    const float* __restrict__ W3, const float* __restrict__ b3,
    float* __restrict__ out) {
  __shared__ float sS[64][132];
  int t = threadIdx.x;
  {
    int e = t >> 2, qq = t & 3;
    int eg = (blockIdx.x << 6) + e;
    int g0 = ei[eg], g1 = ei[NE + eg];
    float av = ea[eg];
    const float4* p4 = (const float4*)(P + (size_t)g0 * DD + qq * 32);
    const float4* q4 = (const float4*)(Q + (size_t)g1 * DD + qq * 32);
    const float4* w4 = (const float4*)(w1e + qq * 32);
    const float4* b4 = (const float4*)(b1 + qq * 32);
    #pragma unroll
    for (int m = 0; m < 8; ++m) {
      float4 p = p4[m], qv = q4[m], wv = w4[m], bv = b4[m];
      float4 sv;
      sv.x = siluf(fmaf(av, wv.x, (p.x + qv.x) + bv.x));
      sv.y = siluf(fmaf(av, wv.y, (p.y + qv.y) + bv.y));
      sv.z = siluf(fmaf(av, wv.z, (p.z + qv.z) + bv.z));
      sv.w = siluf(fmaf(av, wv.w, (p.w + qv.w) + bv.w));
      *(float4*)&sS[e][(qq << 5) + (m << 2)] = sv;
    }
  }
  __syncthreads();
  int ti = t >> 4, tj = t & 15;
  float4 acc[4] = {{0.f,0.f,0.f,0.f},{0.f,0.f,0.f,0.f},{0.f,0.f,0.f,0.f},{0.f,0.f,0.f,0.f}};
  const float4* W2g = (const float4*)W2;
  #pragma unroll 4
  for (int k4 = 0; k4 < 32; ++k4) {
    float4 sv[4], wv[4];
    #pragma unroll
    for (int r = 0; r < 4; ++r)
      sv[r] = *(const float4*)&sS[(ti << 2) + r][k4 << 2];
    #pragma unroll
    for (int kk = 0; kk < 4; ++kk)
      wv[kk] = W2g[(((k4 << 2) + kk) << 4) + tj];
    #pragma unroll
    for (int r = 0; r < 4; ++r) {
      acc[r].x = fmaf(sv[r].x, wv[0].x, acc[r].x);
      acc[r].y = fmaf(sv[r].x, wv[0].y, acc[r].y);
      acc[r].z = fmaf(sv[r].x, wv[0].z, acc[r].z);
      acc[r].w = fmaf(sv[r].x, wv[0].w, acc[r].w);
      acc[r].x = fmaf(sv[r].y, wv[1].x, acc[r].x);
      acc[r].y = fmaf(sv[r].y, wv[1].y, acc[r].y);
      acc[r].z = fmaf(sv[r].y, wv[1].z, acc[r].z);
      acc[r].w = fmaf(sv[r].y, wv[1].w, acc[r].w);
      acc[r].x = fmaf(sv[r].z, wv[2].x, acc[r].x);
      acc[r].y = fmaf(sv[r].z, wv[2].y, acc[r].y);
      acc[r].z = fmaf(sv[r].z, wv[2].z, acc[r].z);
      acc[r].w = fmaf(sv[r].z, wv[2].w, acc[r].w);
      acc[r].x = fmaf(sv[r].w, wv[3].x, acc[r].x);
      acc[r].y = fmaf(sv[r].w, wv[3].y, acc[r].y);
      acc[r].z = fmaf(sv[r].w, wv[3].z, acc[r].z);
      acc[r].w = fmaf(sv[r].w, wv[3].w, acc[r].w);
    }
  }
  float4 b2v = *(const float4*)(b2 + (tj << 2));
  float4 w3v = *(const float4*)(W3 + (tj << 2));
  float b3v = b3[0];
  #pragma unroll
  for (int r = 0; r < 4; ++r) {
    float part = siluf(acc[r].x + b2v.x) * w3v.x;
    part = fmaf(siluf(acc[r].y + b2v.y), w3v.y, part);
    part = fmaf(siluf(acc[r].z + b2v.z), w3v.z, part);
    part = fmaf(siluf(acc[r].w + b2v.w), w3v.w, part);
    part = sum16(part);
    if (tj == 0)
      out[(blockIdx.x << 6) + (ti << 2) + r] = tanhf(part + b3v);
  }
}

// ---------------- launcher ----------------
extern "C" void kernel_launch(void* const* d_in, const int* in_sizes, int n_in,
                              void* d_out, int out_size, void* d_ws, size_t ws_size,
                              hipStream_t stream) {
  const float* x     = (const float*)d_in[0];
  const int*   ei    = (const int*)  d_in[1];
  const float* ea    = (const float*)d_in[2];
  const float* encW  = (const float*)d_in[4];
  const float* encb  = (const float*)d_in[5];
  const float* msgW  = (const float*)d_in[6];
  const float* msgb  = (const float*)d_in[7];
  const float* msgg  = (const float*)d_in[8];
  const float* msgbe = (const float*)d_in[9];
  const float* updW  = (const float*)d_in[10];
  const float* updb  = (const float*)d_in[11];
  const float* updg  = (const float*)d_in[12];
  const float* updbe = (const float*)d_in[13];
  const float* dW1   = (const float*)d_in[14];
  const float* db1   = (const float*)d_in[15];
  const float* dW2   = (const float*)d_in[16];
  const float* db2   = (const float*)d_in[17];
  const float* dW3   = (const float*)d_in[18];
  const float* db3   = (const float*)d_in[19];
  float* out = (float*)d_out;

  float* h     = (float*)d_ws;              // BN*DD
  float* adj   = h     + BN * DD;           // NB*NN*NN
  float* hT    = adj   + NB * NN * NN;      // BN*DD (t = h@Wt + mb; decoder P)
  float* hS    = hT    + BN * DD;           // BN*DD (s = h@Ws; decoder Q)
  float* agg   = hS    + BN * DD;           // BN*DD
  float* statT = agg   + BN * DD;           // BN*4
  float* statS = statT + BN * 4;            // BN*4
  float* wst   = statS + BN * 4;            // 8
  float* MR4   = wst   + 8;                 // NB*NN*NN*4 (rstd, -mean*rstd, a, 0)

  hipMemsetAsync(adj, 0, (size_t)NB * NN * NN * sizeof(float), stream);
  k_encode<<<512, 256, 0, stream>>>(x, encW, encb, h);
  k_scatter<<<NE / 256, 256, 0, stream>>>(ei, ea, adj);
  k_wprep<<<NL, 64, 0, stream>>>(msgW, wst);

  for (int l = 0; l < NL; ++l) {
    const float* Wl = msgW + (size_t)l * (2 * DD + 1) * DD;
    const float* wjl = Wl + 2 * DD * DD;
    k_gemm2<<<BN / 8, 256, 0, stream>>>(h, Wl, Wl + DD * DD, msgb + l * DD, wjl,
                                        hT, hS, statT, statS);
    k_ts<<<256, 256, 0, stream>>>(hT, hS, adj, statT, statS, wst + 2 * l, MR4);
    k_messages<<<1024, 512, 0, stream>>>(hT, hS, MR4, wjl,
        msgg + l * DD, msgbe + l * DD, agg);
    k_update<<<BN / 8, 256, 0, stream>>>(h, agg, updW + (size_t)l * 2 * DD * DD,
        updb + l * DD, updg + l * DD, updbe + l * DD);
  }

  k_gemm2<<<BN / 8, 256, 0, stream>>>(h, dW1, dW1 + DD * DD, nullptr, nullptr,
                                      hT, hS, statT, statS);
  k_decoder<<<NE / 64, 256, 0, stream>>>(ei, ea, hT, hS, dW1 + 2 * DD * DD, db1,
      dW2, db2, dW3, db3, out);
}